// Round 8
// baseline (160.104 us; speedup 1.0000x reference)
//
#include <hip/hip_runtime.h>
#include <hip/hip_bf16.h>

#define BB 8
#define SS 1024
#define DD 1024
#define HH 16

typedef __attribute__((ext_vector_type(8))) short short8;
typedef __attribute__((ext_vector_type(8))) __bf16 bf16x8;
typedef __attribute__((ext_vector_type(4))) float f32x4;

__device__ inline float bf2f(unsigned short h){
  unsigned u = ((unsigned)h) << 16;
  return __builtin_bit_cast(float, u);
}
__device__ inline unsigned short f2bf(float f){
  unsigned u = __builtin_bit_cast(unsigned, f);
  u += 0x7fffu + ((u >> 16) & 1u);   // round-to-nearest-even
  return (unsigned short)(u >> 16);
}
__device__ inline f32x4 mfma16(short8 a, short8 b, f32x4 c){
  return __builtin_amdgcn_mfma_f32_16x16x32_bf16(
      __builtin_bit_cast(bf16x8, a), __builtin_bit_cast(bf16x8, b), c, 0, 0, 0);
}
__device__ inline void gld_lds16(const unsigned short* g, unsigned short* l){
  __builtin_amdgcn_global_load_lds((const __attribute__((address_space(1))) void*)g,
      (__attribute__((address_space(3))) void*)l, 16, 0, 0);
}

// ---------------- weight transpose + cast: wT[n][k] = bf16(w[k][n]) ----------------
__global__ __launch_bounds__(256) void prep_w(const float* __restrict__ w1,
                                              const float* __restrict__ w2,
                                              unsigned short* __restrict__ w1T,
                                              unsigned short* __restrict__ w2T){
  __shared__ float tile[64][65];
  const float* src = blockIdx.z ? w2 : w1;
  unsigned short* dst = blockIdx.z ? w2T : w1T;
  int k0 = blockIdx.x * 64, n0 = blockIdx.y * 64;
  int tx = threadIdx.x & 63, ty = threadIdx.x >> 6;
#pragma unroll
  for (int r = 0; r < 16; ++r)
    tile[ty + 4*r][tx] = src[(k0 + ty + 4*r) * DD + n0 + tx];
  __syncthreads();
#pragma unroll
  for (int r = 0; r < 16; ++r)
    dst[(n0 + ty + 4*r) * DD + k0 + tx] = f2bf(tile[tx][ty + 4*r]);
}

// ---------------- q prep: PERMUTED fragment-major layouts ----------------
// kf chunk (bh, g:0..31, c:0..1, hf:0..1), lane (lr,lg), elem e:
//   row = g*32 + (lr>>2)*8 + c*4 + (lr&3)   (key/query slot permutation)
//   d   = hf*32 + lg*8 + e                  (normalized * sqrt(log2 e))
// vf[bh][kt32][db][lane][8] : d = db*16 + (lane&15), k = kt32*32 + (lane>>4)*8 + e
// qb : bf16 copy of q (row-major)
__global__ __launch_bounds__(256) void prep_q(const float* __restrict__ q,
                                              unsigned short* __restrict__ kf,
                                              unsigned short* __restrict__ vf,
                                              unsigned short* __restrict__ qb){
  __shared__ float tile[64][65];
  __shared__ float rinv[64];
  int bh = blockIdx.x >> 4, st = blockIdx.x & 15;
  int b = bh >> 4, h = bh & 15;
  int t = threadIdx.x;
  int tx = t & 63, ty = t >> 6;
  int srow = b * SS + st * 64;
#pragma unroll
  for (int r = 0; r < 16; ++r)
    tile[ty + 4*r][tx] = q[(size_t)(srow + ty + 4*r) * DD + h * 64 + tx];
  __syncthreads();
  {
    int s = t >> 2, p = t & 3;
    float ssum = 0.f;
#pragma unroll
    for (int i = 0; i < 16; ++i){ float v = tile[s][p*16 + i]; ssum += v * v; }
    ssum += __shfl_xor(ssum, 1);
    ssum += __shfl_xor(ssum, 2);
    if (p == 0) rinv[s] = 1.0f / fmaxf(sqrtf(ssum), 1e-8f);
  }
  __syncthreads();
  // qb: plain bf16 copy
#pragma unroll
  for (int r = 0; r < 16; ++r)
    qb[(size_t)(srow + ty + 4*r) * DD + h * 64 + tx] = f2bf(tile[ty + 4*r][tx]);
  // kf: 8 permuted sub-frags per 64-row tile; scale folds log2(e) into QK^T
#pragma unroll
  for (int v = 0; v < 2; ++v){
    int idx = t * 2 + v;              // 0..511
    int c_l = idx >> 6, lane = idx & 63;
    int g2 = c_l >> 2, c = (c_l >> 1) & 1, hf = c_l & 1;
    int lrq = lane & 15, lgq = lane >> 4;
    int s = g2 * 32 + (lrq >> 2) * 8 + c * 4 + (lrq & 3);
    int d0 = hf * 32 + lgq * 8;
    float rv = rinv[s] * 1.20112240878645f;   // sqrt(log2 e)
    short8 o;
#pragma unroll
    for (int e = 0; e < 8; ++e) o[e] = (short)f2bf(tile[s][d0 + e] * rv);
    *(short8*)(kf + ((size_t)(bh * 128 + st * 8 + c_l) * 64 + lane) * 8) = o;
  }
  // vf: 2 kt-tiles x 4 dblocks per block
#pragma unroll
  for (int v = 0; v < 2; ++v){
    int idx = t * 2 + v;              // 0..511
    int kt2 = idx >> 8, db = (idx >> 6) & 3, lane = idx & 63;
    int d = db * 16 + (lane & 15);
    int k0 = kt2 * 32 + (lane >> 4) * 8;
    short8 o;
#pragma unroll
    for (int e = 0; e < 8; ++e) o[e] = (short)f2bf(tile[k0 + e][d]);
    *(short8*)(vf + ((size_t)((bh * 32 + st * 2 + kt2) * 4 + db) * 512 + lane * 8)) = o;
  }
}

// ---------------- attention v8: no LDS, no barriers — direct L2-resident fragment reads ----
__global__ __launch_bounds__(256, 3) void attn_kern(const unsigned short* __restrict__ kf,
                                                    const unsigned short* __restrict__ vf,
                                                    const int* __restrict__ masks,
                                                    unsigned short* __restrict__ attnb){
  const int bh = blockIdx.x, b = bh >> 4, h = bh & 15;
  const int by = blockIdx.y;                 // 0..7
  const int t = threadIdx.x, w = t >> 6, l = t & 63;
  const int lr = l & 15, lg = l >> 4;
  const int gq = by * 4 + w;                 // q-group (32 rows) owned by this wave

  // Q B-frags (normalized, permuted slots)
  short8 aQ[2][2];
#pragma unroll
  for (int c = 0; c < 2; ++c)
#pragma unroll
    for (int hf = 0; hf < 2; ++hf)
      aQ[c][hf] = *(const short8*)(kf +
          ((size_t)(bh * 128 + gq * 4 + c * 2 + hf) * 64 + l) * 8);

  const short ONEB = (short)0x3F80;   // bf16 1.0
  const short8 ones = {ONEB, ONEB, ONEB, ONEB, ONEB, ONEB, ONEB, ONEB};

  f32x4 o[2][4] = {};
  f32x4 rsacc[2] = {};

  const unsigned short* kbase = kf + (size_t)bh * 128 * 512 + (size_t)l * 8;
  const unsigned short* vbase = vf + (size_t)bh * 32 * 2048 + (size_t)l * 8;

#pragma unroll 2
  for (int g = 0; g < 32; ++g){              // 32 key-groups of 32 keys
    // K sub-frags + V sub-frags straight from global (L2-hit, lane-linear)
    short8 bK[2][2], bV[4];
#pragma unroll
    for (int c = 0; c < 2; ++c)
#pragma unroll
      for (int hf = 0; hf < 2; ++hf)
        bK[c][hf] = *(const short8*)(kbase + (size_t)(g * 4 + c * 2 + hf) * 512);
#pragma unroll
    for (int db = 0; db < 4; ++db)
      bV[db] = *(const short8*)(vbase + (size_t)(g * 4 + db) * 512);
    // swapped QK^T: lane holds P[key-slot][q=lr]; scores pre-scaled by log2(e)
    f32x4 sc[2][2];
#pragma unroll
    for (int qc = 0; qc < 2; ++qc)
#pragma unroll
      for (int c = 0; c < 2; ++c){
        f32x4 z = {0.f, 0.f, 0.f, 0.f};
        z = mfma16(bK[c][0], aQ[qc][0], z);
        z = mfma16(bK[c][1], aQ[qc][1], z);
        sc[qc][c] = z;
      }
    // p = exp2(sc) — single v_exp_f32 per value (softmax is scale-invariant)
    bf16x8 pav[2];
#pragma unroll
    for (int qc = 0; qc < 2; ++qc)
#pragma unroll
      for (int c = 0; c < 2; ++c)
#pragma unroll
        for (int j = 0; j < 4; ++j){
          float x = sc[qc][c][j], pv;
          asm("v_exp_f32 %0, %1" : "=v"(pv) : "v"(x));
          pav[qc][c * 4 + j] = (__bf16)pv;
        }
    short8 pa0 = __builtin_bit_cast(short8, pav[0]);
    short8 pa1 = __builtin_bit_cast(short8, pav[1]);
    // rsum on the matrix pipe: rsacc[qc][j] = sum_k P[k][q=lg*4+j]
    rsacc[0] = mfma16(pa0, ones, rsacc[0]);
    rsacc[1] = mfma16(pa1, ones, rsacc[1]);
    // PV
#pragma unroll
    for (int db = 0; db < 4; ++db){
      o[0][db] = mfma16(pa0, bV[db], o[0][db]);
      o[1][db] = mfma16(pa1, bV[db], o[1][db]);
    }
  }

  // epilogue: denominator already at the right lanes/regs (zero shuffles)
#pragma unroll
  for (int qc = 0; qc < 2; ++qc){
    float invj[4];
#pragma unroll
    for (int j = 0; j < 4; ++j) invj[j] = 1.0f / rsacc[qc][j];
#pragma unroll
    for (int db = 0; db < 4; ++db)
#pragma unroll
      for (int j = 0; j < 4; ++j){
        int qrow = by * 128 + w * 32 + lg * 8 + qc * 4 + j;
        float val = o[qc][db][j] * invj[j];
        if (masks[b * SS + qrow] == 0){
          float vs = 0.f;
          for (int kt = 0; kt < 32; ++kt)
            for (int lgp = 0; lgp < 4; ++lgp){
              const unsigned short* vp = vf +
                  ((size_t)((bh * 32 + kt) * 4 + db) * 512 + (lgp * 16 + lr) * 8);
              for (int e = 0; e < 8; ++e) vs += bf2f(vp[e]);
            }
          val = -1e9f * vs;
        }
        attnb[(size_t)(b * SS + qrow) * DD + h * 64 + db * 16 + lr] = f2bf(val);
      }
  }
}

// ---------------- block row reduce (sum, sumsq) over 256 threads ----------------
__device__ inline float2 block_reduce2(float a, float bq){
  __shared__ float sm[8];
#pragma unroll
  for (int off = 1; off < 64; off <<= 1){
    a += __shfl_xor(a, off);
    bq += __shfl_xor(bq, off);
  }
  int w = threadIdx.x >> 6;
  if ((threadIdx.x & 63) == 0){ sm[2*w] = a; sm[2*w + 1] = bq; }
  __syncthreads();
  float2 r;
  r.x = sm[0] + sm[2] + sm[4] + sm[6];
  r.y = sm[1] + sm[3] + sm[5] + sm[7];
  __syncthreads();
  return r;
}

// ---------------- y1 = LN(qb + attn); writes bf16 ----------------
__global__ __launch_bounds__(256) void addnorm1(const unsigned short* __restrict__ qb,
                                                const unsigned short* __restrict__ attnb,
                                                const float* __restrict__ g,
                                                const float* __restrict__ bt,
                                                unsigned short* __restrict__ y1b){
  int row = blockIdx.x, t = threadIdx.x;
  ushort4 qv = *(const ushort4*)(qb + (size_t)row * DD + t * 4);
  ushort4 av = *(const ushort4*)(attnb + (size_t)row * DD + t * 4);
  float x[4] = { bf2f(qv.x) + bf2f(av.x), bf2f(qv.y) + bf2f(av.y),
                 bf2f(qv.z) + bf2f(av.z), bf2f(qv.w) + bf2f(av.w) };
  float s = 0.f, ssq = 0.f;
#pragma unroll
  for (int i = 0; i < 4; ++i){ s += x[i]; ssq += x[i] * x[i]; }
  float2 r = block_reduce2(s, ssq);
  float m = r.x * (1.0f / DD);
  float rs = rsqrtf(r.y * (1.0f / DD) - m * m + 1e-5f);
  float4 gv = *(const float4*)(g + t * 4);
  float4 bv = *(const float4*)(bt + t * 4);
  float y[4] = { (x[0]-m)*rs*gv.x + bv.x, (x[1]-m)*rs*gv.y + bv.y,
                 (x[2]-m)*rs*gv.z + bv.z, (x[3]-m)*rs*gv.w + bv.w };
  ushort4 ob = { f2bf(y[0]), f2bf(y[1]), f2bf(y[2]), f2bf(y[3]) };
  *(ushort4*)(y1b + (size_t)row * DD + t * 4) = ob;
}

// ---------------- GEMM v3: 3-buffer counted-vmcnt + XCD-chunked swizzle ----------------
__global__ __launch_bounds__(256, 2) void gemm_bias(const unsigned short* __restrict__ X,
                                                    const unsigned short* __restrict__ WT,
                                                    const float* __restrict__ bias,
                                                    unsigned short* __restrict__ out){
  __shared__ unsigned short As[3][128 * 32];
  __shared__ unsigned short Bs[3][128 * 32];
  int t = threadIdx.x, l = t & 63, w = t >> 6;
  int wm = w >> 1, wn = w & 1;
  int lr = l & 15, lg = l >> 4;
  // XCD-chunked swizzle: XCD x works bx in [8x, 8x+8) x all by -> 2MB A + 2MB B per L2
  int id = blockIdx.x;
  int bm = (((id & 7) << 3) + ((id >> 3) & 7)) * 128;
  int bn = (id >> 6) * 128;
  f32x4 acc[4][4] = {};
  int r = t >> 2, cb = (t & 3) * 8;

#define GSTAGE(kt, bf) do {                                                        \
    gld_lds16(X  + (size_t)(bm +      r) * 1024 + (kt) * 32 + cb,                  \
              &As[bf][w * 512]);                                                   \
    gld_lds16(X  + (size_t)(bm + 64 + r) * 1024 + (kt) * 32 + cb,                  \
              &As[bf][2048 + w * 512]);                                            \
    gld_lds16(WT + (size_t)(bn +      r) * 1024 + (kt) * 32 + cb,                  \
              &Bs[bf][w * 512]);                                                   \
    gld_lds16(WT + (size_t)(bn + 64 + r) * 1024 + (kt) * 32 + cb,                  \
              &Bs[bf][2048 + w * 512]);                                            \
  } while (0)

  GSTAGE(0, 0);
  GSTAGE(1, 1);
  asm volatile("s_waitcnt vmcnt(4)" ::: "memory");   // kt0 landed
  __builtin_amdgcn_s_barrier();

  for (int kt = 0; kt < 32; ++kt){
    const int cur = kt % 3;
    if (kt + 2 < 32) GSTAGE(kt + 2, (kt + 2) % 3);
    short8 aA[4], bB[4];
#pragma unroll
    for (int i = 0; i < 4; ++i)
      aA[i] = *(const short8*)&As[cur][(wm * 64 + i * 16 + lr) * 32 + lg * 8];
#pragma unroll
    for (int i = 0; i < 4; ++i)
      bB[i] = *(const short8*)&Bs[cur][(wn * 64 + i * 16 + lr) * 32 + lg * 8];
#pragma unroll
    for (int mi = 0; mi < 4; ++mi)
#pragma unroll
      for (int ni = 0; ni < 4; ++ni)
        acc[mi][ni] = mfma16(aA[mi], bB[ni], acc[mi][ni]);
    if (kt + 1 < 32){
      asm volatile("s_waitcnt lgkmcnt(0)" ::: "memory");
      if (kt + 2 < 32) asm volatile("s_waitcnt vmcnt(4)" ::: "memory"); // kt+1 landed
      else             asm volatile("s_waitcnt vmcnt(0)" ::: "memory");
      __builtin_amdgcn_s_barrier();
    }
  }
#undef GSTAGE
#pragma unroll
  for (int ni = 0; ni < 4; ++ni){
    int col = bn + wn * 64 + ni * 16 + lr;
    float bv = bias[col];
#pragma unroll
    for (int mi = 0; mi < 4; ++mi){
      int row0 = bm + wm * 64 + mi * 16 + lg * 4;
#pragma unroll
      for (int j = 0; j < 4; ++j)
        out[(size_t)(row0 + j) * 1024 + col] = f2bf(acc[mi][ni][j] + bv);
    }
  }
}

// ---------------- h = leaky(LN(g1)) ----------------
__global__ __launch_bounds__(256) void ln_leaky(const unsigned short* __restrict__ in,
                                                const float* __restrict__ g,
                                                const float* __restrict__ bt,
                                                unsigned short* __restrict__ out){
  int row = blockIdx.x, t = threadIdx.x;
  ushort4 iv = *(const ushort4*)(in + (size_t)row * DD + t * 4);
  float x[4] = { bf2f(iv.x), bf2f(iv.y), bf2f(iv.z), bf2f(iv.w) };
  float s = 0.f, ssq = 0.f;
#pragma unroll
  for (int i = 0; i < 4; ++i){ s += x[i]; ssq += x[i] * x[i]; }
  float2 r = block_reduce2(s, ssq);
  float m = r.x * (1.0f / DD);
  float rs = rsqrtf(r.y * (1.0f / DD) - m * m + 1e-5f);
  float4 gv = *(const float4*)(g + t * 4);
  float4 bv = *(const float4*)(bt + t * 4);
  ushort4 ov;
  {
    float v0 = (x[0]-m)*rs*gv.x + bv.x; v0 = v0 >= 0.f ? v0 : 0.01f*v0; ov.x = f2bf(v0);
    float v1 = (x[1]-m)*rs*gv.y + bv.y; v1 = v1 >= 0.f ? v1 : 0.01f*v1; ov.y = f2bf(v1);
    float v2 = (x[2]-m)*rs*gv.z + bv.z; v2 = v2 >= 0.f ? v2 : 0.01f*v2; ov.z = f2bf(v2);
    float v3 = (x[3]-m)*rs*gv.w + bv.w; v3 = v3 >= 0.f ? v3 : 0.01f*v3; ov.w = f2bf(v3);
  }
  *(ushort4*)(out + (size_t)row * DD + t * 4) = ov;
}

// ---------------- final: y=leaky(LN(g2)); y2=LN(y1+y); out=LN(y1+y2) ----------------
__global__ __launch_bounds__(256) void final_kern(const unsigned short* __restrict__ g2,
                                                  const unsigned short* __restrict__ y1,
                                                  const float* __restrict__ ln2g, const float* __restrict__ ln2b,
                                                  const float* __restrict__ anfg, const float* __restrict__ anfb,
                                                  const float* __restrict__ an2g, const float* __restrict__ an2b,
                                                  float* __restrict__ out){
  int row = blockIdx.x, t = threadIdx.x;
  ushort4 iv = *(const ushort4*)(g2 + (size_t)row * DD + t * 4);
  ushort4 y1v = *(const ushort4*)(y1 + (size_t)row * DD + t * 4);
  float x[4] = { bf2f(iv.x), bf2f(iv.y), bf2f(iv.z), bf2f(iv.w) };
  float yy1[4] = { bf2f(y1v.x), bf2f(y1v.y), bf2f(y1v.z), bf2f(y1v.w) };
  float s = 0.f, ssq = 0.f;
#pragma unroll
  for (int i = 0; i < 4; ++i){ s += x[i]; ssq += x[i]*x[i]; }
  float2 r = block_reduce2(s, ssq);
  float m = r.x * (1.0f / DD);
  float rs = rsqrtf(r.y * (1.0f / DD) - m*m + 1e-5f);
  float4 gv = *(const float4*)(ln2g + t * 4);
  float4 bv = *(const float4*)(ln2b + t * 4);
  float y[4] = { (x[0]-m)*rs*gv.x + bv.x, (x[1]-m)*rs*gv.y + bv.y,
                 (x[2]-m)*rs*gv.z + bv.z, (x[3]-m)*rs*gv.w + bv.w };
#pragma unroll
  for (int i = 0; i < 4; ++i) y[i] = y[i] >= 0.f ? y[i] : 0.01f*y[i];

  float tv[4]; s = 0.f; ssq = 0.f;
#pragma unroll
  for (int i = 0; i < 4; ++i){ tv[i] = yy1[i] + y[i]; s += tv[i]; ssq += tv[i]*tv[i]; }
  r = block_reduce2(s, ssq);
  m = r.x * (1.0f / DD);
  rs = rsqrtf(r.y * (1.0f / DD) - m*m + 1e-5f);
  gv = *(const float4*)(anfg + t * 4);
  bv = *(const float4*)(anfb + t * 4);
  float y2[4] = { (tv[0]-m)*rs*gv.x + bv.x, (tv[1]-m)*rs*gv.y + bv.y,
                  (tv[2]-m)*rs*gv.z + bv.z, (tv[3]-m)*rs*gv.w + bv.w };

  float u[4]; s = 0.f; ssq = 0.f;
#pragma unroll
  for (int i = 0; i < 4; ++i){ u[i] = yy1[i] + y2[i]; s += u[i]; ssq += u[i]*u[i]; }
  r = block_reduce2(s, ssq);
  m = r.x * (1.0f / DD);
  rs = rsqrtf(r.y * (1.0f / DD) - m*m + 1e-5f);
  gv = *(const float4*)(an2g + t * 4);
  bv = *(const float4*)(an2b + t * 4);
  float4 ov = { (u[0]-m)*rs*gv.x + bv.x, (u[1]-m)*rs*gv.y + bv.y,
                (u[2]-m)*rs*gv.z + bv.z, (u[3]-m)*rs*gv.w + bv.w };
  *(float4*)(out + (size_t)row * DD + t * 4) = ov;
}

extern "C" void kernel_launch(void* const* d_in, const int* in_sizes, int n_in,
                              void* d_out, int out_size, void* d_ws, size_t ws_size,
                              hipStream_t stream){
  const float* q    = (const float*)d_in[0];
  const int* masks  = (const int*)d_in[1];
  const float* w1   = (const float*)d_in[2];
  const float* b1   = (const float*)d_in[3];
  const float* ln1g = (const float*)d_in[4];
  const float* ln1b = (const float*)d_in[5];
  const float* w2   = (const float*)d_in[6];
  const float* b2   = (const float*)d_in[7];
  const float* ln2g = (const float*)d_in[8];
  const float* ln2b = (const float*)d_in[9];
  const float* anfg = (const float*)d_in[10];
  const float* anfb = (const float*)d_in[11];
  const float* an1g = (const float*)d_in[12];
  const float* an1b = (const float*)d_in[13];
  const float* an2g = (const float*)d_in[14];
  const float* an2b = (const float*)d_in[15];

  char* ws = (char*)d_ws;
  unsigned short* w1T  = (unsigned short*)(ws + 0);          //  2 MB
  unsigned short* w2T  = (unsigned short*)(ws + 2097152);    //  2 MB
  unsigned short* kf   = (unsigned short*)(ws + 4194304);    // 16 MB  (reused: g1)
  unsigned short* vf   = (unsigned short*)(ws + 20971520);   // 16 MB  (reused: h)
  unsigned short* attn = (unsigned short*)(ws + 37748736);   // 16 MB  (reused: g2)
  unsigned short* y1b  = (unsigned short*)(ws + 54525952);   // 16 MB
  unsigned short* qb   = (unsigned short*)(ws + 71303168);   // 16 MB  -> total 88 MB
  unsigned short* g1   = kf;
  unsigned short* hbuf = vf;
  unsigned short* g2   = attn;
  float* outp = (float*)d_out;

  prep_w<<<dim3(16, 16, 2), 256, 0, stream>>>(w1, w2, w1T, w2T);
  prep_q<<<dim3(2048), 256, 0, stream>>>(q, kf, vf, qb);
  attn_kern<<<dim3(128, 8), 256, 0, stream>>>(kf, vf, masks, attn);
  addnorm1<<<dim3(8192), 256, 0, stream>>>(qb, attn, an1g, an1b, y1b);
  gemm_bias<<<dim3(512), 256, 0, stream>>>(y1b, w1T, b1, g1);
  ln_leaky<<<dim3(8192), 256, 0, stream>>>(g1, ln1g, ln1b, hbuf);
  gemm_bias<<<dim3(512), 256, 0, stream>>>(hbuf, w2T, b2, g2);
  final_kern<<<dim3(8192), 256, 0, stream>>>(g2, y1b, ln2g, ln2b, anfg, anfb, an2g, an2b, outp);
}

// Round 9
// 155.059 us; speedup vs baseline: 1.0325x; 1.0325x over previous
//
#include <hip/hip_runtime.h>
#include <hip/hip_bf16.h>

#define BB 8
#define SS 1024
#define DD 1024
#define HH 16

typedef __attribute__((ext_vector_type(8))) short short8;
typedef __attribute__((ext_vector_type(8))) __bf16 bf16x8;
typedef __attribute__((ext_vector_type(4))) float f32x4;

__device__ inline float bf2f(unsigned short h){
  unsigned u = ((unsigned)h) << 16;
  return __builtin_bit_cast(float, u);
}
__device__ inline unsigned short f2bf(float f){
  unsigned u = __builtin_bit_cast(unsigned, f);
  u += 0x7fffu + ((u >> 16) & 1u);   // round-to-nearest-even
  return (unsigned short)(u >> 16);
}
__device__ inline f32x4 mfma16(short8 a, short8 b, f32x4 c){
  return __builtin_amdgcn_mfma_f32_16x16x32_bf16(
      __builtin_bit_cast(bf16x8, a), __builtin_bit_cast(bf16x8, b), c, 0, 0, 0);
}
__device__ inline void gld_lds16(const unsigned short* g, unsigned short* l){
  __builtin_amdgcn_global_load_lds((const __attribute__((address_space(1))) void*)g,
      (__attribute__((address_space(3))) void*)l, 16, 0, 0);
}

// ---------------- weight transpose + cast: wT[n][k] = bf16(w[k][n]) ----------------
__global__ __launch_bounds__(256) void prep_w(const float* __restrict__ w1,
                                              const float* __restrict__ w2,
                                              unsigned short* __restrict__ w1T,
                                              unsigned short* __restrict__ w2T){
  __shared__ float tile[64][65];
  const float* src = blockIdx.z ? w2 : w1;
  unsigned short* dst = blockIdx.z ? w2T : w1T;
  int k0 = blockIdx.x * 64, n0 = blockIdx.y * 64;
  int tx = threadIdx.x & 63, ty = threadIdx.x >> 6;
#pragma unroll
  for (int r = 0; r < 16; ++r)
    tile[ty + 4*r][tx] = src[(k0 + ty + 4*r) * DD + n0 + tx];
  __syncthreads();
#pragma unroll
  for (int r = 0; r < 16; ++r)
    dst[(n0 + ty + 4*r) * DD + k0 + tx] = f2bf(tile[tx][ty + 4*r]);
}

// ---------------- q prep: PERMUTED fragment-major layouts ----------------
// kf chunk (bh, g:0..31, c:0..1, hf:0..1), lane (lr,lg), elem e:
//   row = g*32 + (lr>>2)*8 + c*4 + (lr&3)   (key/query slot permutation)
//   d   = hf*32 + lg*8 + e                  (normalized * sqrt(log2 e))
// vf[bh][kt32][db][lane][8] : d = db*16 + (lane&15), k = kt32*32 + (lane>>4)*8 + e
// qb : bf16 copy of q (row-major)
__global__ __launch_bounds__(256) void prep_q(const float* __restrict__ q,
                                              unsigned short* __restrict__ kf,
                                              unsigned short* __restrict__ vf,
                                              unsigned short* __restrict__ qb){
  __shared__ float tile[64][65];
  __shared__ float rinv[64];
  int bh = blockIdx.x >> 4, st = blockIdx.x & 15;
  int b = bh >> 4, h = bh & 15;
  int t = threadIdx.x;
  int tx = t & 63, ty = t >> 6;
  int srow = b * SS + st * 64;
#pragma unroll
  for (int r = 0; r < 16; ++r)
    tile[ty + 4*r][tx] = q[(size_t)(srow + ty + 4*r) * DD + h * 64 + tx];
  __syncthreads();
  {
    int s = t >> 2, p = t & 3;
    float ssum = 0.f;
#pragma unroll
    for (int i = 0; i < 16; ++i){ float v = tile[s][p*16 + i]; ssum += v * v; }
    ssum += __shfl_xor(ssum, 1);
    ssum += __shfl_xor(ssum, 2);
    if (p == 0) rinv[s] = 1.0f / fmaxf(sqrtf(ssum), 1e-8f);
  }
  __syncthreads();
  // qb: plain bf16 copy
#pragma unroll
  for (int r = 0; r < 16; ++r)
    qb[(size_t)(srow + ty + 4*r) * DD + h * 64 + tx] = f2bf(tile[ty + 4*r][tx]);
  // kf: 8 permuted sub-frags per 64-row tile; scale folds log2(e) into QK^T
#pragma unroll
  for (int v = 0; v < 2; ++v){
    int idx = t * 2 + v;              // 0..511
    int c_l = idx >> 6, lane = idx & 63;
    int g2 = c_l >> 2, c = (c_l >> 1) & 1, hf = c_l & 1;
    int lrq = lane & 15, lgq = lane >> 4;
    int s = g2 * 32 + (lrq >> 2) * 8 + c * 4 + (lrq & 3);
    int d0 = hf * 32 + lgq * 8;
    float rv = rinv[s] * 1.20112240878645f;   // sqrt(log2 e)
    short8 o;
#pragma unroll
    for (int e = 0; e < 8; ++e) o[e] = (short)f2bf(tile[s][d0 + e] * rv);
    *(short8*)(kf + ((size_t)(bh * 128 + st * 8 + c_l) * 64 + lane) * 8) = o;
  }
  // vf: 2 kt-tiles x 4 dblocks per block
#pragma unroll
  for (int v = 0; v < 2; ++v){
    int idx = t * 2 + v;              // 0..511
    int kt2 = idx >> 8, db = (idx >> 6) & 3, lane = idx & 63;
    int d = db * 16 + (lane & 15);
    int k0 = kt2 * 32 + (lane >> 4) * 8;
    short8 o;
#pragma unroll
    for (int e = 0; e < 8; ++e) o[e] = (short)f2bf(tile[k0 + e][d]);
    *(short8*)(vf + ((size_t)((bh * 32 + st * 2 + kt2) * 4 + db) * 512 + lane * 8)) = o;
  }
}

// ---------------- attention v7 (reverted): exp2-direct, rsum on matrix pipe ----------------
#define NPH 16
__global__ __launch_bounds__(512, 4) void attn_kern(const unsigned short* __restrict__ kf,
                                                    const unsigned short* __restrict__ vf,
                                                    const int* __restrict__ masks,
                                                    unsigned short* __restrict__ attnb){
  __shared__ unsigned short Kb[3][8][512];   // 3 bufs x 8KB (64 keys each)
  __shared__ unsigned short Vb[3][8][512];
  __shared__ int anym;
  const int bh = blockIdx.x, b = bh >> 4, h = bh & 15;
  const int by = blockIdx.y;
  const int t = threadIdx.x, w = t >> 6, l = t & 63;
  const int lr = l & 15, lg = l >> 4;
  if (t == 0) anym = 0;
  __syncthreads();
  if (t < 256 && masks[b * SS + by * 256 + t] == 0) anym = 1;

  // Q B-frags: wave w owns q-group gq = by*8 + w (32 q-rows, 2 chunks)
  short8 aQ[2][2];
#pragma unroll
  for (int c = 0; c < 2; ++c)
#pragma unroll
    for (int hf = 0; hf < 2; ++hf)
      aQ[c][hf] = *(const short8*)(kf +
          ((size_t)(bh * 128 + (by * 8 + w) * 4 + c * 2 + hf) * 64 + l) * 8);

  const short ONEB = (short)0x3F80;   // bf16 1.0
  const short8 ones = {ONEB, ONEB, ONEB, ONEB, ONEB, ONEB, ONEB, ONEB};

  // staging: phase ph covers key groups 2ph, 2ph+1 (64 keys); 2 loads per wave
#define STAGE(ph, bf) do {                                                            \
    if (w < 4){                                                                       \
      gld_lds16(kf + ((size_t)(bh * 128 + (2*(ph)) * 4 + w) * 64 + l) * 8,            \
                &Kb[bf][w][0]);                                                       \
      gld_lds16(kf + ((size_t)(bh * 128 + (2*(ph)+1) * 4 + w) * 64 + l) * 8,          \
                &Kb[bf][4 + w][0]);                                                   \
    } else {                                                                          \
      gld_lds16(vf + ((size_t)((bh * 32 + 2*(ph)) * 4 + (w - 4)) * 512 + l * 8),      \
                &Vb[bf][w - 4][0]);                                                   \
      gld_lds16(vf + ((size_t)((bh * 32 + 2*(ph)+1) * 4 + (w - 4)) * 512 + l * 8),    \
                &Vb[bf][4 + (w - 4)][0]);                                             \
    }                                                                                 \
  } while (0)

  STAGE(0, 0);
  STAGE(1, 1);
  asm volatile("s_waitcnt vmcnt(2) lgkmcnt(0)" ::: "memory");   // ph0 landed, anym visible
  __builtin_amdgcn_s_barrier();

  f32x4 o[2][4] = {};
  f32x4 rsacc[2] = {};

  for (int ph = 0; ph < NPH; ++ph){
    const int cur = ph % 3;
    if (ph + 2 < NPH) STAGE(ph + 2, (ph + 2) % 3);
#pragma unroll
    for (int gi = 0; gi < 2; ++gi){
      // K sub-frags of this 32-key group
      short8 bK[2][2];
#pragma unroll
      for (int c = 0; c < 2; ++c)
#pragma unroll
        for (int hf = 0; hf < 2; ++hf)
          bK[c][hf] = *(const short8*)&Kb[cur][gi * 4 + c * 2 + hf][l * 8];
      // swapped QK^T: lane holds P[key-slot][q=lr]; scores pre-scaled by log2(e)
      f32x4 sc[2][2];
#pragma unroll
      for (int qc = 0; qc < 2; ++qc)
#pragma unroll
        for (int c = 0; c < 2; ++c){
          f32x4 z = {0.f, 0.f, 0.f, 0.f};
          z = mfma16(bK[c][0], aQ[qc][0], z);
          z = mfma16(bK[c][1], aQ[qc][1], z);
          sc[qc][c] = z;
        }
      // p = exp2(sc) — single v_exp_f32 per value (softmax is scale-invariant)
      bf16x8 pav[2];
#pragma unroll
      for (int qc = 0; qc < 2; ++qc)
#pragma unroll
        for (int c = 0; c < 2; ++c)
#pragma unroll
          for (int j = 0; j < 4; ++j){
            float x = sc[qc][c][j], pv;
            asm("v_exp_f32 %0, %1" : "=v"(pv) : "v"(x));
            pav[qc][c * 4 + j] = (__bf16)pv;
          }
      short8 pa0 = __builtin_bit_cast(short8, pav[0]);
      short8 pa1 = __builtin_bit_cast(short8, pav[1]);
      // rsum on the matrix pipe: rsacc[qc][j] = sum_k P[k][q=lg*4+j]
      rsacc[0] = mfma16(pa0, ones, rsacc[0]);
      rsacc[1] = mfma16(pa1, ones, rsacc[1]);
      // PV
#pragma unroll
      for (int db = 0; db < 4; ++db){
        short8 bV = *(const short8*)&Vb[cur][gi * 4 + db][l * 8];
        o[0][db] = mfma16(pa0, bV, o[0][db]);
        o[1][db] = mfma16(pa1, bV, o[1][db]);
      }
    }
    if (ph + 1 < NPH){
      asm volatile("s_waitcnt lgkmcnt(0)" ::: "memory");   // my reads of cur done
      if (ph + 2 < NPH) asm volatile("s_waitcnt vmcnt(2)" ::: "memory"); // ph+1 landed
      else              asm volatile("s_waitcnt vmcnt(0)" ::: "memory");
      __builtin_amdgcn_s_barrier();
    }
  }

  // epilogue: denominator already at the right lanes/regs (zero shuffles)
#pragma unroll
  for (int qc = 0; qc < 2; ++qc){
    float invj[4];
#pragma unroll
    for (int j = 0; j < 4; ++j) invj[j] = 1.0f / rsacc[qc][j];
#pragma unroll
    for (int db = 0; db < 4; ++db)
#pragma unroll
      for (int j = 0; j < 4; ++j){
        int qrow = by * 256 + w * 32 + lg * 8 + qc * 4 + j;
        float val = o[qc][db][j] * invj[j];
        if (anym && masks[b * SS + qrow] == 0){
          float vs = 0.f;
          for (int kt = 0; kt < 32; ++kt)
            for (int lgp = 0; lgp < 4; ++lgp){
              const unsigned short* vp = vf +
                  ((size_t)((bh * 32 + kt) * 4 + db) * 512 + (lgp * 16 + lr) * 8);
              for (int e = 0; e < 8; ++e) vs += bf2f(vp[e]);
            }
          val = -1e9f * vs;
        }
        attnb[(size_t)(b * SS + qrow) * DD + h * 64 + db * 16 + lr] = f2bf(val);
      }
  }
#undef STAGE
}

// ---------------- block row reduce (sum, sumsq) over 256 threads ----------------
__device__ inline float2 block_reduce2(float a, float bq){
  __shared__ float sm[8];
#pragma unroll
  for (int off = 1; off < 64; off <<= 1){
    a += __shfl_xor(a, off);
    bq += __shfl_xor(bq, off);
  }
  int w = threadIdx.x >> 6;
  if ((threadIdx.x & 63) == 0){ sm[2*w] = a; sm[2*w + 1] = bq; }
  __syncthreads();
  float2 r;
  r.x = sm[0] + sm[2] + sm[4] + sm[6];
  r.y = sm[1] + sm[3] + sm[5] + sm[7];
  __syncthreads();
  return r;
}

// ---------------- y1 = LN(qb + attn); writes bf16 ----------------
__global__ __launch_bounds__(256) void addnorm1(const unsigned short* __restrict__ qb,
                                                const unsigned short* __restrict__ attnb,
                                                const float* __restrict__ g,
                                                const float* __restrict__ bt,
                                                unsigned short* __restrict__ y1b){
  int row = blockIdx.x, t = threadIdx.x;
  ushort4 qv = *(const ushort4*)(qb + (size_t)row * DD + t * 4);
  ushort4 av = *(const ushort4*)(attnb + (size_t)row * DD + t * 4);
  float x[4] = { bf2f(qv.x) + bf2f(av.x), bf2f(qv.y) + bf2f(av.y),
                 bf2f(qv.z) + bf2f(av.z), bf2f(qv.w) + bf2f(av.w) };
  float s = 0.f, ssq = 0.f;
#pragma unroll
  for (int i = 0; i < 4; ++i){ s += x[i]; ssq += x[i] * x[i]; }
  float2 r = block_reduce2(s, ssq);
  float m = r.x * (1.0f / DD);
  float rs = rsqrtf(r.y * (1.0f / DD) - m * m + 1e-5f);
  float4 gv = *(const float4*)(g + t * 4);
  float4 bv = *(const float4*)(bt + t * 4);
  float y[4] = { (x[0]-m)*rs*gv.x + bv.x, (x[1]-m)*rs*gv.y + bv.y,
                 (x[2]-m)*rs*gv.z + bv.z, (x[3]-m)*rs*gv.w + bv.w };
  ushort4 ob = { f2bf(y[0]), f2bf(y[1]), f2bf(y[2]), f2bf(y[3]) };
  *(ushort4*)(y1b + (size_t)row * DD + t * 4) = ob;
}

// ---------------- GEMM v2: 3-buffer counted-vmcnt single-barrier loop (no swizzle) ----------------
__global__ __launch_bounds__(256, 2) void gemm_bias(const unsigned short* __restrict__ X,
                                                    const unsigned short* __restrict__ WT,
                                                    const float* __restrict__ bias,
                                                    unsigned short* __restrict__ out){
  __shared__ unsigned short As[3][128 * 32];
  __shared__ unsigned short Bs[3][128 * 32];
  int t = threadIdx.x, l = t & 63, w = t >> 6;
  int wm = w >> 1, wn = w & 1;
  int lr = l & 15, lg = l >> 4;
  int bm = blockIdx.x * 128, bn = blockIdx.y * 128;
  f32x4 acc[4][4] = {};
  int r = t >> 2, cb = (t & 3) * 8;

#define GSTAGE(kt, bf) do {                                                        \
    gld_lds16(X  + (size_t)(bm +      r) * 1024 + (kt) * 32 + cb,                  \
              &As[bf][w * 512]);                                                   \
    gld_lds16(X  + (size_t)(bm + 64 + r) * 1024 + (kt) * 32 + cb,                  \
              &As[bf][2048 + w * 512]);                                            \
    gld_lds16(WT + (size_t)(bn +      r) * 1024 + (kt) * 32 + cb,                  \
              &Bs[bf][w * 512]);                                                   \
    gld_lds16(WT + (size_t)(bn + 64 + r) * 1024 + (kt) * 32 + cb,                  \
              &Bs[bf][2048 + w * 512]);                                            \
  } while (0)

  GSTAGE(0, 0);
  GSTAGE(1, 1);
  asm volatile("s_waitcnt vmcnt(4)" ::: "memory");   // kt0 landed
  __builtin_amdgcn_s_barrier();

  for (int kt = 0; kt < 32; ++kt){
    const int cur = kt % 3;
    if (kt + 2 < 32) GSTAGE(kt + 2, (kt + 2) % 3);
    short8 aA[4], bB[4];
#pragma unroll
    for (int i = 0; i < 4; ++i)
      aA[i] = *(const short8*)&As[cur][(wm * 64 + i * 16 + lr) * 32 + lg * 8];
#pragma unroll
    for (int i = 0; i < 4; ++i)
      bB[i] = *(const short8*)&Bs[cur][(wn * 64 + i * 16 + lr) * 32 + lg * 8];
#pragma unroll
    for (int mi = 0; mi < 4; ++mi)
#pragma unroll
      for (int ni = 0; ni < 4; ++ni)
        acc[mi][ni] = mfma16(aA[mi], bB[ni], acc[mi][ni]);
    if (kt + 1 < 32){
      asm volatile("s_waitcnt lgkmcnt(0)" ::: "memory");
      if (kt + 2 < 32) asm volatile("s_waitcnt vmcnt(4)" ::: "memory"); // kt+1 landed
      else             asm volatile("s_waitcnt vmcnt(0)" ::: "memory");
      __builtin_amdgcn_s_barrier();
    }
  }
#undef GSTAGE
#pragma unroll
  for (int ni = 0; ni < 4; ++ni){
    int col = bn + wn * 64 + ni * 16 + lr;
    float bv = bias[col];
#pragma unroll
    for (int mi = 0; mi < 4; ++mi){
      int row0 = bm + wm * 64 + mi * 16 + lg * 4;
#pragma unroll
      for (int j = 0; j < 4; ++j)
        out[(size_t)(row0 + j) * 1024 + col] = f2bf(acc[mi][ni][j] + bv);
    }
  }
}

// ---------------- h = leaky(LN(g1)) ----------------
__global__ __launch_bounds__(256) void ln_leaky(const unsigned short* __restrict__ in,
                                                const float* __restrict__ g,
                                                const float* __restrict__ bt,
                                                unsigned short* __restrict__ out){
  int row = blockIdx.x, t = threadIdx.x;
  ushort4 iv = *(const ushort4*)(in + (size_t)row * DD + t * 4);
  float x[4] = { bf2f(iv.x), bf2f(iv.y), bf2f(iv.z), bf2f(iv.w) };
  float s = 0.f, ssq = 0.f;
#pragma unroll
  for (int i = 0; i < 4; ++i){ s += x[i]; ssq += x[i] * x[i]; }
  float2 r = block_reduce2(s, ssq);
  float m = r.x * (1.0f / DD);
  float rs = rsqrtf(r.y * (1.0f / DD) - m * m + 1e-5f);
  float4 gv = *(const float4*)(g + t * 4);
  float4 bv = *(const float4*)(bt + t * 4);
  ushort4 ov;
  {
    float v0 = (x[0]-m)*rs*gv.x + bv.x; v0 = v0 >= 0.f ? v0 : 0.01f*v0; ov.x = f2bf(v0);
    float v1 = (x[1]-m)*rs*gv.y + bv.y; v1 = v1 >= 0.f ? v1 : 0.01f*v1; ov.y = f2bf(v1);
    float v2 = (x[2]-m)*rs*gv.z + bv.z; v2 = v2 >= 0.f ? v2 : 0.01f*v2; ov.z = f2bf(v2);
    float v3 = (x[3]-m)*rs*gv.w + bv.w; v3 = v3 >= 0.f ? v3 : 0.01f*v3; ov.w = f2bf(v3);
  }
  *(ushort4*)(out + (size_t)row * DD + t * 4) = ov;
}

// ---------------- final: y=leaky(LN(g2)); y2=LN(y1+y); out=LN(y1+y2) ----------------
__global__ __launch_bounds__(256) void final_kern(const unsigned short* __restrict__ g2,
                                                  const unsigned short* __restrict__ y1,
                                                  const float* __restrict__ ln2g, const float* __restrict__ ln2b,
                                                  const float* __restrict__ anfg, const float* __restrict__ anfb,
                                                  const float* __restrict__ an2g, const float* __restrict__ an2b,
                                                  float* __restrict__ out){
  int row = blockIdx.x, t = threadIdx.x;
  ushort4 iv = *(const ushort4*)(g2 + (size_t)row * DD + t * 4);
  ushort4 y1v = *(const ushort4*)(y1 + (size_t)row * DD + t * 4);
  float x[4] = { bf2f(iv.x), bf2f(iv.y), bf2f(iv.z), bf2f(iv.w) };
  float yy1[4] = { bf2f(y1v.x), bf2f(y1v.y), bf2f(y1v.z), bf2f(y1v.w) };
  float s = 0.f, ssq = 0.f;
#pragma unroll
  for (int i = 0; i < 4; ++i){ s += x[i]; ssq += x[i]*x[i]; }
  float2 r = block_reduce2(s, ssq);
  float m = r.x * (1.0f / DD);
  float rs = rsqrtf(r.y * (1.0f / DD) - m*m + 1e-5f);
  float4 gv = *(const float4*)(ln2g + t * 4);
  float4 bv = *(const float4*)(ln2b + t * 4);
  float y[4] = { (x[0]-m)*rs*gv.x + bv.x, (x[1]-m)*rs*gv.y + bv.y,
                 (x[2]-m)*rs*gv.z + bv.z, (x[3]-m)*rs*gv.w + bv.w };
#pragma unroll
  for (int i = 0; i < 4; ++i) y[i] = y[i] >= 0.f ? y[i] : 0.01f*y[i];

  float tv[4]; s = 0.f; ssq = 0.f;
#pragma unroll
  for (int i = 0; i < 4; ++i){ tv[i] = yy1[i] + y[i]; s += tv[i]; ssq += tv[i]*tv[i]; }
  r = block_reduce2(s, ssq);
  m = r.x * (1.0f / DD);
  rs = rsqrtf(r.y * (1.0f / DD) - m*m + 1e-5f);
  gv = *(const float4*)(anfg + t * 4);
  bv = *(const float4*)(anfb + t * 4);
  float y2[4] = { (tv[0]-m)*rs*gv.x + bv.x, (tv[1]-m)*rs*gv.y + bv.y,
                  (tv[2]-m)*rs*gv.z + bv.z, (tv[3]-m)*rs*gv.w + bv.w };

  float u[4]; s = 0.f; ssq = 0.f;
#pragma unroll
  for (int i = 0; i < 4; ++i){ u[i] = yy1[i] + y2[i]; s += u[i]; ssq += u[i]*u[i]; }
  r = block_reduce2(s, ssq);
  m = r.x * (1.0f / DD);
  rs = rsqrtf(r.y * (1.0f / DD) - m*m + 1e-5f);
  gv = *(const float4*)(an2g + t * 4);
  bv = *(const float4*)(an2b + t * 4);
  float4 ov = { (u[0]-m)*rs*gv.x + bv.x, (u[1]-m)*rs*gv.y + bv.y,
                (u[2]-m)*rs*gv.z + bv.z, (u[3]-m)*rs*gv.w + bv.w };
  *(float4*)(out + (size_t)row * DD + t * 4) = ov;
}

extern "C" void kernel_launch(void* const* d_in, const int* in_sizes, int n_in,
                              void* d_out, int out_size, void* d_ws, size_t ws_size,
                              hipStream_t stream){
  const float* q    = (const float*)d_in[0];
  const int* masks  = (const int*)d_in[1];
  const float* w1   = (const float*)d_in[2];
  const float* b1   = (const float*)d_in[3];
  const float* ln1g = (const float*)d_in[4];
  const float* ln1b = (const float*)d_in[5];
  const float* w2   = (const float*)d_in[6];
  const float* b2   = (const float*)d_in[7];
  const float* ln2g = (const float*)d_in[8];
  const float* ln2b = (const float*)d_in[9];
  const float* anfg = (const float*)d_in[10];
  const float* anfb = (const float*)d_in[11];
  const float* an1g = (const float*)d_in[12];
  const float* an1b = (const float*)d_in[13];
  const float* an2g = (const float*)d_in[14];
  const float* an2b = (const float*)d_in[15];

  char* ws = (char*)d_ws;
  unsigned short* w1T  = (unsigned short*)(ws + 0);          //  2 MB
  unsigned short* w2T  = (unsigned short*)(ws + 2097152);    //  2 MB
  unsigned short* kf   = (unsigned short*)(ws + 4194304);    // 16 MB  (reused: g1)
  unsigned short* vf   = (unsigned short*)(ws + 20971520);   // 16 MB  (reused: h)
  unsigned short* attn = (unsigned short*)(ws + 37748736);   // 16 MB  (reused: g2)
  unsigned short* y1b  = (unsigned short*)(ws + 54525952);   // 16 MB
  unsigned short* qb   = (unsigned short*)(ws + 71303168);   // 16 MB  -> total 88 MB
  unsigned short* g1   = kf;
  unsigned short* hbuf = vf;
  unsigned short* g2   = attn;
  float* outp = (float*)d_out;

  prep_w<<<dim3(16, 16, 2), 256, 0, stream>>>(w1, w2, w1T, w2T);
  prep_q<<<dim3(2048), 256, 0, stream>>>(q, kf, vf, qb);
  attn_kern<<<dim3(128, 4), 512, 0, stream>>>(kf, vf, masks, attn);
  addnorm1<<<dim3(8192), 256, 0, stream>>>(qb, attn, an1g, an1b, y1b);
  gemm_bias<<<dim3(64, 8), 256, 0, stream>>>(y1b, w1T, b1, g1);
  ln_leaky<<<dim3(8192), 256, 0, stream>>>(g1, ln1g, ln1b, hbuf);
  gemm_bias<<<dim3(64, 8), 256, 0, stream>>>(hbuf, w2T, b2, g2);
  final_kern<<<dim3(8192), 256, 0, stream>>>(g2, y1b, ln2g, ln2b, anfg, anfb, an2g, an2b, outp);
}

// Round 10
// 144.147 us; speedup vs baseline: 1.1107x; 1.0757x over previous
//
#include <hip/hip_runtime.h>
#include <hip/hip_bf16.h>

#define BB 8
#define SS 1024
#define DD 1024
#define HH 16

typedef __attribute__((ext_vector_type(8))) short short8;
typedef __attribute__((ext_vector_type(8))) __bf16 bf16x8;
typedef __attribute__((ext_vector_type(4))) float f32x4;

__device__ inline float bf2f(unsigned short h){
  unsigned u = ((unsigned)h) << 16;
  return __builtin_bit_cast(float, u);
}
__device__ inline unsigned short f2bf(float f){
  unsigned u = __builtin_bit_cast(unsigned, f);
  u += 0x7fffu + ((u >> 16) & 1u);   // round-to-nearest-even
  return (unsigned short)(u >> 16);
}
__device__ inline f32x4 mfma16(short8 a, short8 b, f32x4 c){
  return __builtin_amdgcn_mfma_f32_16x16x32_bf16(
      __builtin_bit_cast(bf16x8, a), __builtin_bit_cast(bf16x8, b), c, 0, 0, 0);
}
__device__ inline void gld_lds16(const unsigned short* g, unsigned short* l){
  __builtin_amdgcn_global_load_lds((const __attribute__((address_space(1))) void*)g,
      (__attribute__((address_space(3))) void*)l, 16, 0, 0);
}

// ---------------- weight transpose + cast: wT[n][k] = bf16(w[k][n]) ----------------
__global__ __launch_bounds__(256) void prep_w(const float* __restrict__ w1,
                                              const float* __restrict__ w2,
                                              unsigned short* __restrict__ w1T,
                                              unsigned short* __restrict__ w2T){
  __shared__ float tile[64][65];
  const float* src = blockIdx.z ? w2 : w1;
  unsigned short* dst = blockIdx.z ? w2T : w1T;
  int k0 = blockIdx.x * 64, n0 = blockIdx.y * 64;
  int tx = threadIdx.x & 63, ty = threadIdx.x >> 6;
#pragma unroll
  for (int r = 0; r < 16; ++r)
    tile[ty + 4*r][tx] = src[(k0 + ty + 4*r) * DD + n0 + tx];
  __syncthreads();
#pragma unroll
  for (int r = 0; r < 16; ++r)
    dst[(n0 + ty + 4*r) * DD + k0 + tx] = f2bf(tile[tx][ty + 4*r]);
}

// ---------------- q prep: PERMUTED fragment-major layouts ----------------
__global__ __launch_bounds__(256) void prep_q(const float* __restrict__ q,
                                              unsigned short* __restrict__ kf,
                                              unsigned short* __restrict__ vf,
                                              unsigned short* __restrict__ qb){
  __shared__ float tile[64][65];
  __shared__ float rinv[64];
  int bh = blockIdx.x >> 4, st = blockIdx.x & 15;
  int b = bh >> 4, h = bh & 15;
  int t = threadIdx.x;
  int tx = t & 63, ty = t >> 6;
  int srow = b * SS + st * 64;
#pragma unroll
  for (int r = 0; r < 16; ++r)
    tile[ty + 4*r][tx] = q[(size_t)(srow + ty + 4*r) * DD + h * 64 + tx];
  __syncthreads();
  {
    int s = t >> 2, p = t & 3;
    float ssum = 0.f;
#pragma unroll
    for (int i = 0; i < 16; ++i){ float v = tile[s][p*16 + i]; ssum += v * v; }
    ssum += __shfl_xor(ssum, 1);
    ssum += __shfl_xor(ssum, 2);
    if (p == 0) rinv[s] = 1.0f / fmaxf(sqrtf(ssum), 1e-8f);
  }
  __syncthreads();
#pragma unroll
  for (int r = 0; r < 16; ++r)
    qb[(size_t)(srow + ty + 4*r) * DD + h * 64 + tx] = f2bf(tile[ty + 4*r][tx]);
#pragma unroll
  for (int v = 0; v < 2; ++v){
    int idx = t * 2 + v;              // 0..511
    int c_l = idx >> 6, lane = idx & 63;
    int g2 = c_l >> 2, c = (c_l >> 1) & 1, hf = c_l & 1;
    int lrq = lane & 15, lgq = lane >> 4;
    int s = g2 * 32 + (lrq >> 2) * 8 + c * 4 + (lrq & 3);
    int d0 = hf * 32 + lgq * 8;
    float rv = rinv[s] * 1.20112240878645f;   // sqrt(log2 e)
    short8 o;
#pragma unroll
    for (int e = 0; e < 8; ++e) o[e] = (short)f2bf(tile[s][d0 + e] * rv);
    *(short8*)(kf + ((size_t)(bh * 128 + st * 8 + c_l) * 64 + lane) * 8) = o;
  }
#pragma unroll
  for (int v = 0; v < 2; ++v){
    int idx = t * 2 + v;              // 0..511
    int kt2 = idx >> 8, db = (idx >> 6) & 3, lane = idx & 63;
    int d = db * 16 + (lane & 15);
    int k0 = kt2 * 32 + (lane >> 4) * 8;
    short8 o;
#pragma unroll
    for (int e = 0; e < 8; ++e) o[e] = (short)f2bf(tile[k0 + e][d]);
    *(short8*)(vf + ((size_t)((bh * 32 + st * 2 + kt2) * 4 + db) * 512 + lane * 8)) = o;
  }
}

// ---------------- attention v7 (frozen): exp2-direct, rsum on matrix pipe ----------------
#define NPH 16
__global__ __launch_bounds__(512, 4) void attn_kern(const unsigned short* __restrict__ kf,
                                                    const unsigned short* __restrict__ vf,
                                                    const int* __restrict__ masks,
                                                    unsigned short* __restrict__ attnb){
  __shared__ unsigned short Kb[3][8][512];
  __shared__ unsigned short Vb[3][8][512];
  __shared__ int anym;
  const int bh = blockIdx.x, b = bh >> 4, h = bh & 15;
  const int by = blockIdx.y;
  const int t = threadIdx.x, w = t >> 6, l = t & 63;
  const int lr = l & 15, lg = l >> 4;
  if (t == 0) anym = 0;
  __syncthreads();
  if (t < 256 && masks[b * SS + by * 256 + t] == 0) anym = 1;

  short8 aQ[2][2];
#pragma unroll
  for (int c = 0; c < 2; ++c)
#pragma unroll
    for (int hf = 0; hf < 2; ++hf)
      aQ[c][hf] = *(const short8*)(kf +
          ((size_t)(bh * 128 + (by * 8 + w) * 4 + c * 2 + hf) * 64 + l) * 8);

  const short ONEB = (short)0x3F80;
  const short8 ones = {ONEB, ONEB, ONEB, ONEB, ONEB, ONEB, ONEB, ONEB};

#define STAGE(ph, bf) do {                                                            \
    if (w < 4){                                                                       \
      gld_lds16(kf + ((size_t)(bh * 128 + (2*(ph)) * 4 + w) * 64 + l) * 8,            \
                &Kb[bf][w][0]);                                                       \
      gld_lds16(kf + ((size_t)(bh * 128 + (2*(ph)+1) * 4 + w) * 64 + l) * 8,          \
                &Kb[bf][4 + w][0]);                                                   \
    } else {                                                                          \
      gld_lds16(vf + ((size_t)((bh * 32 + 2*(ph)) * 4 + (w - 4)) * 512 + l * 8),      \
                &Vb[bf][w - 4][0]);                                                   \
      gld_lds16(vf + ((size_t)((bh * 32 + 2*(ph)+1) * 4 + (w - 4)) * 512 + l * 8),    \
                &Vb[bf][4 + (w - 4)][0]);                                             \
    }                                                                                 \
  } while (0)

  STAGE(0, 0);
  STAGE(1, 1);
  asm volatile("s_waitcnt vmcnt(2) lgkmcnt(0)" ::: "memory");
  __builtin_amdgcn_s_barrier();

  f32x4 o[2][4] = {};
  f32x4 rsacc[2] = {};

  for (int ph = 0; ph < NPH; ++ph){
    const int cur = ph % 3;
    if (ph + 2 < NPH) STAGE(ph + 2, (ph + 2) % 3);
#pragma unroll
    for (int gi = 0; gi < 2; ++gi){
      short8 bK[2][2];
#pragma unroll
      for (int c = 0; c < 2; ++c)
#pragma unroll
        for (int hf = 0; hf < 2; ++hf)
          bK[c][hf] = *(const short8*)&Kb[cur][gi * 4 + c * 2 + hf][l * 8];
      f32x4 sc[2][2];
#pragma unroll
      for (int qc = 0; qc < 2; ++qc)
#pragma unroll
        for (int c = 0; c < 2; ++c){
          f32x4 z = {0.f, 0.f, 0.f, 0.f};
          z = mfma16(bK[c][0], aQ[qc][0], z);
          z = mfma16(bK[c][1], aQ[qc][1], z);
          sc[qc][c] = z;
        }
      bf16x8 pav[2];
#pragma unroll
      for (int qc = 0; qc < 2; ++qc)
#pragma unroll
        for (int c = 0; c < 2; ++c)
#pragma unroll
          for (int j = 0; j < 4; ++j){
            float x = sc[qc][c][j], pv;
            asm("v_exp_f32 %0, %1" : "=v"(pv) : "v"(x));
            pav[qc][c * 4 + j] = (__bf16)pv;
          }
      short8 pa0 = __builtin_bit_cast(short8, pav[0]);
      short8 pa1 = __builtin_bit_cast(short8, pav[1]);
      rsacc[0] = mfma16(pa0, ones, rsacc[0]);
      rsacc[1] = mfma16(pa1, ones, rsacc[1]);
#pragma unroll
      for (int db = 0; db < 4; ++db){
        short8 bV = *(const short8*)&Vb[cur][gi * 4 + db][l * 8];
        o[0][db] = mfma16(pa0, bV, o[0][db]);
        o[1][db] = mfma16(pa1, bV, o[1][db]);
      }
    }
    if (ph + 1 < NPH){
      asm volatile("s_waitcnt lgkmcnt(0)" ::: "memory");
      if (ph + 2 < NPH) asm volatile("s_waitcnt vmcnt(2)" ::: "memory");
      else              asm volatile("s_waitcnt vmcnt(0)" ::: "memory");
      __builtin_amdgcn_s_barrier();
    }
  }

#pragma unroll
  for (int qc = 0; qc < 2; ++qc){
    float invj[4];
#pragma unroll
    for (int j = 0; j < 4; ++j) invj[j] = 1.0f / rsacc[qc][j];
#pragma unroll
    for (int db = 0; db < 4; ++db)
#pragma unroll
      for (int j = 0; j < 4; ++j){
        int qrow = by * 256 + w * 32 + lg * 8 + qc * 4 + j;
        float val = o[qc][db][j] * invj[j];
        if (anym && masks[b * SS + qrow] == 0){
          float vs = 0.f;
          for (int kt = 0; kt < 32; ++kt)
            for (int lgp = 0; lgp < 4; ++lgp){
              const unsigned short* vp = vf +
                  ((size_t)((bh * 32 + kt) * 4 + db) * 512 + (lgp * 16 + lr) * 8);
              for (int e = 0; e < 8; ++e) vs += bf2f(vp[e]);
            }
          val = -1e9f * vs;
        }
        attnb[(size_t)(b * SS + qrow) * DD + h * 64 + db * 16 + lr] = f2bf(val);
      }
  }
#undef STAGE
}

// ---------------- 2-row block reduce: 256 thr = 2 rows x 128 thr (2 waves each) ----------------
__device__ inline float2 br2(float a, float bq){
  __shared__ float sm[8];
#pragma unroll
  for (int off = 1; off < 64; off <<= 1){
    a += __shfl_xor(a, off);
    bq += __shfl_xor(bq, off);
  }
  int w = threadIdx.x >> 6;
  if ((threadIdx.x & 63) == 0){ sm[w * 2] = a; sm[w * 2 + 1] = bq; }
  __syncthreads();
  int base = (threadIdx.x >> 7) * 4;
  float2 r;
  r.x = sm[base] + sm[base + 2];
  r.y = sm[base + 1] + sm[base + 3];
  __syncthreads();
  return r;
}

// ---------------- y1 = LN(qb + attn); 2 rows/block, 16B loads ----------------
__global__ __launch_bounds__(256) void addnorm1(const unsigned short* __restrict__ qb,
                                                const unsigned short* __restrict__ attnb,
                                                const float* __restrict__ g,
                                                const float* __restrict__ bt,
                                                unsigned short* __restrict__ y1b){
  int rg = threadIdx.x >> 7, tt = threadIdx.x & 127;
  int row = blockIdx.x * 2 + rg;
  short8 qv = *(const short8*)(qb + (size_t)row * DD + tt * 8);
  short8 av = *(const short8*)(attnb + (size_t)row * DD + tt * 8);
  float x[8]; float s = 0.f, ssq = 0.f;
#pragma unroll
  for (int i = 0; i < 8; ++i){
    x[i] = bf2f((unsigned short)qv[i]) + bf2f((unsigned short)av[i]);
    s += x[i]; ssq += x[i] * x[i];
  }
  float2 r = br2(s, ssq);
  float m = r.x * (1.0f / DD);
  float rs = rsqrtf(r.y * (1.0f / DD) - m * m + 1e-5f);
  float4 g0 = *(const float4*)(g + tt * 8), g1 = *(const float4*)(g + tt * 8 + 4);
  float4 b0 = *(const float4*)(bt + tt * 8), b1 = *(const float4*)(bt + tt * 8 + 4);
  float gg[8] = {g0.x,g0.y,g0.z,g0.w,g1.x,g1.y,g1.z,g1.w};
  float bb[8] = {b0.x,b0.y,b0.z,b0.w,b1.x,b1.y,b1.z,b1.w};
  short8 ob;
#pragma unroll
  for (int i = 0; i < 8; ++i) ob[i] = (short)f2bf((x[i]-m)*rs*gg[i] + bb[i]);
  *(short8*)(y1b + (size_t)row * DD + tt * 8) = ob;
}

// ---------------- GEMM v4: counted-vmcnt + setprio + LDS-coalesced epilogue ----------------
__global__ __launch_bounds__(256, 2) void gemm_bias(const unsigned short* __restrict__ X,
                                                    const unsigned short* __restrict__ WT,
                                                    const float* __restrict__ bias,
                                                    unsigned short* __restrict__ out){
  __shared__ unsigned short LDSB[24576];   // 48KB: As = [0,12288), Bs = [12288,24576)
  int t = threadIdx.x, l = t & 63, w = t >> 6;
  int wm = w >> 1, wn = w & 1;
  int lr = l & 15, lg = l >> 4;
  int bm = blockIdx.x * 128, bn = blockIdx.y * 128;
  f32x4 acc[4][4] = {};
  int r = t >> 2, cb = (t & 3) * 8;

#define ASP(bf) (LDSB + (bf) * 4096)
#define BSP(bf) (LDSB + 12288 + (bf) * 4096)
#define GSTAGE(kt, bf) do {                                                        \
    gld_lds16(X  + (size_t)(bm +      r) * 1024 + (kt) * 32 + cb,                  \
              ASP(bf) + w * 512);                                                  \
    gld_lds16(X  + (size_t)(bm + 64 + r) * 1024 + (kt) * 32 + cb,                  \
              ASP(bf) + 2048 + w * 512);                                           \
    gld_lds16(WT + (size_t)(bn +      r) * 1024 + (kt) * 32 + cb,                  \
              BSP(bf) + w * 512);                                                  \
    gld_lds16(WT + (size_t)(bn + 64 + r) * 1024 + (kt) * 32 + cb,                  \
              BSP(bf) + 2048 + w * 512);                                           \
  } while (0)

  GSTAGE(0, 0);
  GSTAGE(1, 1);
  asm volatile("s_waitcnt vmcnt(4)" ::: "memory");
  __builtin_amdgcn_s_barrier();

  for (int kt = 0; kt < 32; ++kt){
    const int cur = kt % 3;
    if (kt + 2 < 32) GSTAGE(kt + 2, (kt + 2) % 3);
    short8 aA[4], bB[4];
#pragma unroll
    for (int i = 0; i < 4; ++i)
      aA[i] = *(const short8*)(ASP(cur) + (wm * 64 + i * 16 + lr) * 32 + lg * 8);
#pragma unroll
    for (int i = 0; i < 4; ++i)
      bB[i] = *(const short8*)(BSP(cur) + (wn * 64 + i * 16 + lr) * 32 + lg * 8);
    __builtin_amdgcn_s_setprio(1);
#pragma unroll
    for (int mi = 0; mi < 4; ++mi)
#pragma unroll
      for (int ni = 0; ni < 4; ++ni)
        acc[mi][ni] = mfma16(aA[mi], bB[ni], acc[mi][ni]);
    __builtin_amdgcn_s_setprio(0);
    if (kt + 1 < 32){
      asm volatile("s_waitcnt lgkmcnt(0)" ::: "memory");
      if (kt + 2 < 32) asm volatile("s_waitcnt vmcnt(4)" ::: "memory");
      else             asm volatile("s_waitcnt vmcnt(0)" ::: "memory");
      __builtin_amdgcn_s_barrier();
    }
  }
#undef GSTAGE

  // epilogue: frag -> LDS (bf16 + bias) -> coalesced 16B stores
  asm volatile("s_waitcnt lgkmcnt(0)" ::: "memory");   // my frag reads done
  __builtin_amdgcn_s_barrier();                        // all waves done with LDS
#pragma unroll
  for (int ni = 0; ni < 4; ++ni){
    int col = wn * 64 + ni * 16 + lr;
    float bv = bias[bn + col];
#pragma unroll
    for (int mi = 0; mi < 4; ++mi){
      int row0 = wm * 64 + mi * 16 + lg * 4;
#pragma unroll
      for (int j = 0; j < 4; ++j)
        LDSB[(row0 + j) * 128 + col] = f2bf(acc[mi][ni][j] + bv);
    }
  }
  asm volatile("s_waitcnt lgkmcnt(0)" ::: "memory");   // my LDS writes retired
  __builtin_amdgcn_s_barrier();                        // C-tile complete
#pragma unroll
  for (int i = 0; i < 8; ++i){
    int idx = t + i * 256;          // 16B chunk id, 0..2047
    int row = idx >> 4;
    int c8  = idx & 15;
    short8 v = *(const short8*)&LDSB[row * 128 + c8 * 8];
    *(short8*)(out + (size_t)(bm + row) * 1024 + bn + c8 * 8) = v;
  }
#undef ASP
#undef BSP
}

// ---------------- h = leaky(LN(g1)); 2 rows/block, 16B loads ----------------
__global__ __launch_bounds__(256) void ln_leaky(const unsigned short* __restrict__ in,
                                                const float* __restrict__ g,
                                                const float* __restrict__ bt,
                                                unsigned short* __restrict__ out){
  int rg = threadIdx.x >> 7, tt = threadIdx.x & 127;
  int row = blockIdx.x * 2 + rg;
  short8 iv = *(const short8*)(in + (size_t)row * DD + tt * 8);
  float x[8]; float s = 0.f, ssq = 0.f;
#pragma unroll
  for (int i = 0; i < 8; ++i){
    x[i] = bf2f((unsigned short)iv[i]);
    s += x[i]; ssq += x[i] * x[i];
  }
  float2 r = br2(s, ssq);
  float m = r.x * (1.0f / DD);
  float rs = rsqrtf(r.y * (1.0f / DD) - m * m + 1e-5f);
  float4 g0 = *(const float4*)(g + tt * 8), g1 = *(const float4*)(g + tt * 8 + 4);
  float4 b0 = *(const float4*)(bt + tt * 8), b1 = *(const float4*)(bt + tt * 8 + 4);
  float gg[8] = {g0.x,g0.y,g0.z,g0.w,g1.x,g1.y,g1.z,g1.w};
  float bb[8] = {b0.x,b0.y,b0.z,b0.w,b1.x,b1.y,b1.z,b1.w};
  short8 ov;
#pragma unroll
  for (int i = 0; i < 8; ++i){
    float v = (x[i]-m)*rs*gg[i] + bb[i];
    v = v >= 0.f ? v : 0.01f * v;
    ov[i] = (short)f2bf(v);
  }
  *(short8*)(out + (size_t)row * DD + tt * 8) = ov;
}

// ---------------- final: y=leaky(LN(g2)); y2=LN(y1+y); out=LN(y1+y2); 2 rows/block ----------------
__global__ __launch_bounds__(256) void final_kern(const unsigned short* __restrict__ g2,
                                                  const unsigned short* __restrict__ y1,
                                                  const float* __restrict__ ln2g, const float* __restrict__ ln2b,
                                                  const float* __restrict__ anfg, const float* __restrict__ anfb,
                                                  const float* __restrict__ an2g, const float* __restrict__ an2b,
                                                  float* __restrict__ out){
  int rg = threadIdx.x >> 7, tt = threadIdx.x & 127;
  int row = blockIdx.x * 2 + rg;
  short8 iv = *(const short8*)(g2 + (size_t)row * DD + tt * 8);
  short8 yv = *(const short8*)(y1 + (size_t)row * DD + tt * 8);
  float x[8], yy1[8]; float s = 0.f, ssq = 0.f;
#pragma unroll
  for (int i = 0; i < 8; ++i){
    x[i] = bf2f((unsigned short)iv[i]);
    yy1[i] = bf2f((unsigned short)yv[i]);
    s += x[i]; ssq += x[i] * x[i];
  }
  float2 r = br2(s, ssq);
  float m = r.x * (1.0f / DD);
  float rs = rsqrtf(r.y * (1.0f / DD) - m * m + 1e-5f);
  float4 p0, p1;
  p0 = *(const float4*)(ln2g + tt * 8); p1 = *(const float4*)(ln2g + tt * 8 + 4);
  float gg[8] = {p0.x,p0.y,p0.z,p0.w,p1.x,p1.y,p1.z,p1.w};
  p0 = *(const float4*)(ln2b + tt * 8); p1 = *(const float4*)(ln2b + tt * 8 + 4);
  float bb[8] = {p0.x,p0.y,p0.z,p0.w,p1.x,p1.y,p1.z,p1.w};
  float y[8];
#pragma unroll
  for (int i = 0; i < 8; ++i){
    float v = (x[i]-m)*rs*gg[i] + bb[i];
    y[i] = v >= 0.f ? v : 0.01f * v;
  }

  float tv[8]; s = 0.f; ssq = 0.f;
#pragma unroll
  for (int i = 0; i < 8; ++i){ tv[i] = yy1[i] + y[i]; s += tv[i]; ssq += tv[i]*tv[i]; }
  r = br2(s, ssq);
  m = r.x * (1.0f / DD);
  rs = rsqrtf(r.y * (1.0f / DD) - m*m + 1e-5f);
  p0 = *(const float4*)(anfg + tt * 8); p1 = *(const float4*)(anfg + tt * 8 + 4);
  float gg2[8] = {p0.x,p0.y,p0.z,p0.w,p1.x,p1.y,p1.z,p1.w};
  p0 = *(const float4*)(anfb + tt * 8); p1 = *(const float4*)(anfb + tt * 8 + 4);
  float bb2[8] = {p0.x,p0.y,p0.z,p0.w,p1.x,p1.y,p1.z,p1.w};
  float y2[8];
#pragma unroll
  for (int i = 0; i < 8; ++i) y2[i] = (tv[i]-m)*rs*gg2[i] + bb2[i];

  float u[8]; s = 0.f; ssq = 0.f;
#pragma unroll
  for (int i = 0; i < 8; ++i){ u[i] = yy1[i] + y2[i]; s += u[i]; ssq += u[i]*u[i]; }
  r = br2(s, ssq);
  m = r.x * (1.0f / DD);
  rs = rsqrtf(r.y * (1.0f / DD) - m*m + 1e-5f);
  p0 = *(const float4*)(an2g + tt * 8); p1 = *(const float4*)(an2g + tt * 8 + 4);
  float gg3[8] = {p0.x,p0.y,p0.z,p0.w,p1.x,p1.y,p1.z,p1.w};
  p0 = *(const float4*)(an2b + tt * 8); p1 = *(const float4*)(an2b + tt * 8 + 4);
  float bb3[8] = {p0.x,p0.y,p0.z,p0.w,p1.x,p1.y,p1.z,p1.w};
  float4 o0 = { (u[0]-m)*rs*gg3[0] + bb3[0], (u[1]-m)*rs*gg3[1] + bb3[1],
                (u[2]-m)*rs*gg3[2] + bb3[2], (u[3]-m)*rs*gg3[3] + bb3[3] };
  float4 o1 = { (u[4]-m)*rs*gg3[4] + bb3[4], (u[5]-m)*rs*gg3[5] + bb3[5],
                (u[6]-m)*rs*gg3[6] + bb3[6], (u[7]-m)*rs*gg3[7] + bb3[7] };
  *(float4*)(out + (size_t)row * DD + tt * 8) = o0;
  *(float4*)(out + (size_t)row * DD + tt * 8 + 4) = o1;
}

extern "C" void kernel_launch(void* const* d_in, const int* in_sizes, int n_in,
                              void* d_out, int out_size, void* d_ws, size_t ws_size,
                              hipStream_t stream){
  const float* q    = (const float*)d_in[0];
  const int* masks  = (const int*)d_in[1];
  const float* w1   = (const float*)d_in[2];
  const float* b1   = (const float*)d_in[3];
  const float* ln1g = (const float*)d_in[4];
  const float* ln1b = (const float*)d_in[5];
  const float* w2   = (const float*)d_in[6];
  const float* b2   = (const float*)d_in[7];
  const float* ln2g = (const float*)d_in[8];
  const float* ln2b = (const float*)d_in[9];
  const float* anfg = (const float*)d_in[10];
  const float* anfb = (const float*)d_in[11];
  const float* an1g = (const float*)d_in[12];
  const float* an1b = (const float*)d_in[13];
  const float* an2g = (const float*)d_in[14];
  const float* an2b = (const float*)d_in[15];

  char* ws = (char*)d_ws;
  unsigned short* w1T  = (unsigned short*)(ws + 0);          //  2 MB
  unsigned short* w2T  = (unsigned short*)(ws + 2097152);    //  2 MB
  unsigned short* kf   = (unsigned short*)(ws + 4194304);    // 16 MB  (reused: g1)
  unsigned short* vf   = (unsigned short*)(ws + 20971520);   // 16 MB  (reused: h)
  unsigned short* attn = (unsigned short*)(ws + 37748736);   // 16 MB  (reused: g2)
  unsigned short* y1b  = (unsigned short*)(ws + 54525952);   // 16 MB
  unsigned short* qb   = (unsigned short*)(ws + 71303168);   // 16 MB  -> total 88 MB
  unsigned short* g1   = kf;
  unsigned short* hbuf = vf;
  unsigned short* g2   = attn;
  float* outp = (float*)d_out;

  prep_w<<<dim3(16, 16, 2), 256, 0, stream>>>(w1, w2, w1T, w2T);
  prep_q<<<dim3(2048), 256, 0, stream>>>(q, kf, vf, qb);
  attn_kern<<<dim3(128, 4), 512, 0, stream>>>(kf, vf, masks, attn);
  addnorm1<<<dim3(4096), 256, 0, stream>>>(qb, attn, an1g, an1b, y1b);
  gemm_bias<<<dim3(64, 8), 256, 0, stream>>>(y1b, w1T, b1, g1);
  ln_leaky<<<dim3(4096), 256, 0, stream>>>(g1, ln1g, ln1b, hbuf);
  gemm_bias<<<dim3(64, 8), 256, 0, stream>>>(hbuf, w2T, b2, g2);
  final_kern<<<dim3(4096), 256, 0, stream>>>(g2, y1b, ln2g, ln2b, anfg, anfb, an2g, an2b, outp);
}

// Round 11
// 142.464 us; speedup vs baseline: 1.1238x; 1.0118x over previous
//
#include <hip/hip_runtime.h>
#include <hip/hip_bf16.h>

#define BB 8
#define SS 1024
#define DD 1024
#define HH 16

typedef __attribute__((ext_vector_type(8))) short short8;
typedef __attribute__((ext_vector_type(8))) __bf16 bf16x8;
typedef __attribute__((ext_vector_type(4))) float f32x4;

__device__ inline float bf2f(unsigned short h){
  unsigned u = ((unsigned)h) << 16;
  return __builtin_bit_cast(float, u);
}
__device__ inline unsigned short f2bf(float f){
  unsigned u = __builtin_bit_cast(unsigned, f);
  u += 0x7fffu + ((u >> 16) & 1u);   // round-to-nearest-even
  return (unsigned short)(u >> 16);
}
__device__ inline f32x4 mfma16(short8 a, short8 b, f32x4 c){
  return __builtin_amdgcn_mfma_f32_16x16x32_bf16(
      __builtin_bit_cast(bf16x8, a), __builtin_bit_cast(bf16x8, b), c, 0, 0, 0);
}
__device__ inline void gld_lds16(const unsigned short* g, unsigned short* l){
  __builtin_amdgcn_global_load_lds((const __attribute__((address_space(1))) void*)g,
      (__attribute__((address_space(3))) void*)l, 16, 0, 0);
}

// ---------------- weight transpose + cast: wT[n][k] = bf16(w[k][n]) ----------------
__global__ __launch_bounds__(256) void prep_w(const float* __restrict__ w1,
                                              const float* __restrict__ w2,
                                              unsigned short* __restrict__ w1T,
                                              unsigned short* __restrict__ w2T){
  __shared__ float tile[64][65];
  const float* src = blockIdx.z ? w2 : w1;
  unsigned short* dst = blockIdx.z ? w2T : w1T;
  int k0 = blockIdx.x * 64, n0 = blockIdx.y * 64;
  int tx = threadIdx.x & 63, ty = threadIdx.x >> 6;
#pragma unroll
  for (int r = 0; r < 16; ++r)
    tile[ty + 4*r][tx] = src[(k0 + ty + 4*r) * DD + n0 + tx];
  __syncthreads();
#pragma unroll
  for (int r = 0; r < 16; ++r)
    dst[(n0 + ty + 4*r) * DD + k0 + tx] = f2bf(tile[tx][ty + 4*r]);
}

// ---------------- q prep: PERMUTED fragment-major layouts ----------------
__global__ __launch_bounds__(256) void prep_q(const float* __restrict__ q,
                                              unsigned short* __restrict__ kf,
                                              unsigned short* __restrict__ vf,
                                              unsigned short* __restrict__ qb){
  __shared__ float tile[64][65];
  __shared__ float rinv[64];
  int bh = blockIdx.x >> 4, st = blockIdx.x & 15;
  int b = bh >> 4, h = bh & 15;
  int t = threadIdx.x;
  int tx = t & 63, ty = t >> 6;
  int srow = b * SS + st * 64;
#pragma unroll
  for (int r = 0; r < 16; ++r)
    tile[ty + 4*r][tx] = q[(size_t)(srow + ty + 4*r) * DD + h * 64 + tx];
  __syncthreads();
  {
    int s = t >> 2, p = t & 3;
    float ssum = 0.f;
#pragma unroll
    for (int i = 0; i < 16; ++i){ float v = tile[s][p*16 + i]; ssum += v * v; }
    ssum += __shfl_xor(ssum, 1);
    ssum += __shfl_xor(ssum, 2);
    if (p == 0) rinv[s] = 1.0f / fmaxf(sqrtf(ssum), 1e-8f);
  }
  __syncthreads();
#pragma unroll
  for (int r = 0; r < 16; ++r)
    qb[(size_t)(srow + ty + 4*r) * DD + h * 64 + tx] = f2bf(tile[ty + 4*r][tx]);
#pragma unroll
  for (int v = 0; v < 2; ++v){
    int idx = t * 2 + v;              // 0..511
    int c_l = idx >> 6, lane = idx & 63;
    int g2 = c_l >> 2, c = (c_l >> 1) & 1, hf = c_l & 1;
    int lrq = lane & 15, lgq = lane >> 4;
    int s = g2 * 32 + (lrq >> 2) * 8 + c * 4 + (lrq & 3);
    int d0 = hf * 32 + lgq * 8;
    float rv = rinv[s] * 1.20112240878645f;   // sqrt(log2 e)
    short8 o;
#pragma unroll
    for (int e = 0; e < 8; ++e) o[e] = (short)f2bf(tile[s][d0 + e] * rv);
    *(short8*)(kf + ((size_t)(bh * 128 + st * 8 + c_l) * 64 + lane) * 8) = o;
  }
#pragma unroll
  for (int v = 0; v < 2; ++v){
    int idx = t * 2 + v;              // 0..511
    int kt2 = idx >> 8, db = (idx >> 6) & 3, lane = idx & 63;
    int d = db * 16 + (lane & 15);
    int k0 = kt2 * 32 + (lane >> 4) * 8;
    short8 o;
#pragma unroll
    for (int e = 0; e < 8; ++e) o[e] = (short)f2bf(tile[k0 + e][d]);
    *(short8*)(vf + ((size_t)((bh * 32 + st * 2 + kt2) * 4 + db) * 512 + lane * 8)) = o;
  }
}

// ---------------- attention v9: 64 q-rows/wave (4 q-chunks), 2x LDS reuse ----------------
#define NPH 16
__global__ __launch_bounds__(256, 2) void attn_kern(const unsigned short* __restrict__ kf,
                                                    const unsigned short* __restrict__ vf,
                                                    const int* __restrict__ masks,
                                                    unsigned short* __restrict__ attnb){
  __shared__ unsigned short Kb[3][8][512];   // 3 bufs x 8KB (64 keys each)
  __shared__ unsigned short Vb[3][8][512];
  __shared__ int anym;
  const int bh = blockIdx.x, b = bh >> 4, h = bh & 15;
  const int by = blockIdx.y;                 // 0..3, 256 q-rows per block
  const int t = threadIdx.x, w = t >> 6, l = t & 63;
  const int lr = l & 15, lg = l >> 4;
  if (t == 0) anym = 0;
  __syncthreads();
  if (masks[b * SS + by * 256 + t] == 0) anym = 1;

  // Q B-frags: wave w owns groups by*8 + w*2 + {0,1}; qc -> (group qc>>1, chunk qc&1)
  short8 aQ[4][2];
#pragma unroll
  for (int qc = 0; qc < 4; ++qc)
#pragma unroll
    for (int hf = 0; hf < 2; ++hf)
      aQ[qc][hf] = *(const short8*)(kf +
          ((size_t)(bh * 128 + (by * 8 + w * 2 + (qc >> 1)) * 4 + (qc & 1) * 2 + hf) * 64 + l) * 8);

  const short ONEB = (short)0x3F80;
  const short8 ones = {ONEB, ONEB, ONEB, ONEB, ONEB, ONEB, ONEB, ONEB};

  // staging: phase ph = key groups 2ph, 2ph+1 (64 keys); 4 loads per wave
  // w=0: Kb[0..3] (grp 2ph), w=1: Kb[4..7] (grp 2ph+1), w=2: Vb[0..3], w=3: Vb[4..7]
#define STAGE(ph, bf) do {                                                            \
    if (w < 2){                                                                       \
      _Pragma("unroll")                                                               \
      for (int i = 0; i < 4; ++i)                                                     \
        gld_lds16(kf + ((size_t)(bh * 128 + (2*(ph) + w) * 4 + i) * 64 + l) * 8,      \
                  &Kb[bf][w * 4 + i][0]);                                             \
    } else {                                                                          \
      _Pragma("unroll")                                                               \
      for (int i = 0; i < 4; ++i)                                                     \
        gld_lds16(vf + ((size_t)((bh * 32 + 2*(ph) + (w - 2)) * 4 + i) * 512 + l * 8),\
                  &Vb[bf][(w - 2) * 4 + i][0]);                                       \
    }                                                                                 \
  } while (0)

  STAGE(0, 0);
  STAGE(1, 1);
  asm volatile("s_waitcnt vmcnt(4) lgkmcnt(0)" ::: "memory");   // ph0 landed, anym visible
  __builtin_amdgcn_s_barrier();

  f32x4 o[4][4] = {};
  f32x4 rsacc[4] = {};

  for (int ph = 0; ph < NPH; ++ph){
    const int cur = ph % 3;
    if (ph + 2 < NPH) STAGE(ph + 2, (ph + 2) % 3);
#pragma unroll
    for (int gi = 0; gi < 2; ++gi){
      // K sub-frags of this 32-key group
      short8 bK[2][2];
#pragma unroll
      for (int c = 0; c < 2; ++c)
#pragma unroll
        for (int hf = 0; hf < 2; ++hf)
          bK[c][hf] = *(const short8*)&Kb[cur][gi * 4 + c * 2 + hf][l * 8];
      // swapped QK^T for 4 q-chunks
      f32x4 sc[4][2];
#pragma unroll
      for (int qc = 0; qc < 4; ++qc)
#pragma unroll
        for (int c = 0; c < 2; ++c){
          f32x4 z = {0.f, 0.f, 0.f, 0.f};
          z = mfma16(bK[c][0], aQ[qc][0], z);
          z = mfma16(bK[c][1], aQ[qc][1], z);
          sc[qc][c] = z;
        }
      // p = exp2(sc); registers ARE the PV A-frags
      short8 pa[4];
#pragma unroll
      for (int qc = 0; qc < 4; ++qc){
        bf16x8 pav;
#pragma unroll
        for (int c = 0; c < 2; ++c)
#pragma unroll
          for (int j = 0; j < 4; ++j){
            float x = sc[qc][c][j], pv;
            asm("v_exp_f32 %0, %1" : "=v"(pv) : "v"(x));
            pav[c * 4 + j] = (__bf16)pv;
          }
        pa[qc] = __builtin_bit_cast(short8, pav);
      }
      // rsum on the matrix pipe
#pragma unroll
      for (int qc = 0; qc < 4; ++qc)
        rsacc[qc] = mfma16(pa[qc], ones, rsacc[qc]);
      // PV: each V frag feeds 4 q-chunks
#pragma unroll
      for (int db = 0; db < 4; ++db){
        short8 bV = *(const short8*)&Vb[cur][gi * 4 + db][l * 8];
#pragma unroll
        for (int qc = 0; qc < 4; ++qc)
          o[qc][db] = mfma16(pa[qc], bV, o[qc][db]);
      }
    }
    if (ph + 1 < NPH){
      asm volatile("s_waitcnt lgkmcnt(0)" ::: "memory");   // my reads of cur done
      if (ph + 2 < NPH) asm volatile("s_waitcnt vmcnt(4)" ::: "memory"); // ph+1 landed
      else              asm volatile("s_waitcnt vmcnt(0)" ::: "memory");
      __builtin_amdgcn_s_barrier();
    }
  }

  // epilogue: denominator already at the right lanes/regs
#pragma unroll
  for (int qc = 0; qc < 4; ++qc){
    float invj[4];
#pragma unroll
    for (int j = 0; j < 4; ++j) invj[j] = 1.0f / rsacc[qc][j];
#pragma unroll
    for (int db = 0; db < 4; ++db)
#pragma unroll
      for (int j = 0; j < 4; ++j){
        int qrow = by * 256 + (w * 2 + (qc >> 1)) * 32 + lg * 8 + (qc & 1) * 4 + j;
        float val = o[qc][db][j] * invj[j];
        if (anym && masks[b * SS + qrow] == 0){
          float vs = 0.f;
          for (int kt = 0; kt < 32; ++kt)
            for (int lgp = 0; lgp < 4; ++lgp){
              const unsigned short* vp = vf +
                  ((size_t)((bh * 32 + kt) * 4 + db) * 512 + (lgp * 16 + lr) * 8);
              for (int e = 0; e < 8; ++e) vs += bf2f(vp[e]);
            }
          val = -1e9f * vs;
        }
        attnb[(size_t)(b * SS + qrow) * DD + h * 64 + db * 16 + lr] = f2bf(val);
      }
  }
#undef STAGE
}

// ---------------- 2-row block reduce: 256 thr = 2 rows x 128 thr (2 waves each) ----------------
__device__ inline float2 br2(float a, float bq){
  __shared__ float sm[8];
#pragma unroll
  for (int off = 1; off < 64; off <<= 1){
    a += __shfl_xor(a, off);
    bq += __shfl_xor(bq, off);
  }
  int w = threadIdx.x >> 6;
  if ((threadIdx.x & 63) == 0){ sm[w * 2] = a; sm[w * 2 + 1] = bq; }
  __syncthreads();
  int base = (threadIdx.x >> 7) * 4;
  float2 r;
  r.x = sm[base] + sm[base + 2];
  r.y = sm[base + 1] + sm[base + 3];
  __syncthreads();
  return r;
}

// ---------------- y1 = LN(qb + attn); 2 rows/block, 16B loads ----------------
__global__ __launch_bounds__(256) void addnorm1(const unsigned short* __restrict__ qb,
                                                const unsigned short* __restrict__ attnb,
                                                const float* __restrict__ g,
                                                const float* __restrict__ bt,
                                                unsigned short* __restrict__ y1b){
  int rg = threadIdx.x >> 7, tt = threadIdx.x & 127;
  int row = blockIdx.x * 2 + rg;
  short8 qv = *(const short8*)(qb + (size_t)row * DD + tt * 8);
  short8 av = *(const short8*)(attnb + (size_t)row * DD + tt * 8);
  float x[8]; float s = 0.f, ssq = 0.f;
#pragma unroll
  for (int i = 0; i < 8; ++i){
    x[i] = bf2f((unsigned short)qv[i]) + bf2f((unsigned short)av[i]);
    s += x[i]; ssq += x[i] * x[i];
  }
  float2 r = br2(s, ssq);
  float m = r.x * (1.0f / DD);
  float rs = rsqrtf(r.y * (1.0f / DD) - m * m + 1e-5f);
  float4 g0 = *(const float4*)(g + tt * 8), g1 = *(const float4*)(g + tt * 8 + 4);
  float4 b0 = *(const float4*)(bt + tt * 8), b1 = *(const float4*)(bt + tt * 8 + 4);
  float gg[8] = {g0.x,g0.y,g0.z,g0.w,g1.x,g1.y,g1.z,g1.w};
  float bb[8] = {b0.x,b0.y,b0.z,b0.w,b1.x,b1.y,b1.z,b1.w};
  short8 ob;
#pragma unroll
  for (int i = 0; i < 8; ++i) ob[i] = (short)f2bf((x[i]-m)*rs*gg[i] + bb[i]);
  *(short8*)(y1b + (size_t)row * DD + tt * 8) = ob;
}

// ---------------- GEMM v4: counted-vmcnt + setprio + LDS-coalesced epilogue ----------------
__global__ __launch_bounds__(256, 2) void gemm_bias(const unsigned short* __restrict__ X,
                                                    const unsigned short* __restrict__ WT,
                                                    const float* __restrict__ bias,
                                                    unsigned short* __restrict__ out){
  __shared__ unsigned short LDSB[24576];   // 48KB: As = [0,12288), Bs = [12288,24576)
  int t = threadIdx.x, l = t & 63, w = t >> 6;
  int wm = w >> 1, wn = w & 1;
  int lr = l & 15, lg = l >> 4;
  int bm = blockIdx.x * 128, bn = blockIdx.y * 128;
  f32x4 acc[4][4] = {};
  int r = t >> 2, cb = (t & 3) * 8;

#define ASP(bf) (LDSB + (bf) * 4096)
#define BSP(bf) (LDSB + 12288 + (bf) * 4096)
#define GSTAGE(kt, bf) do {                                                        \
    gld_lds16(X  + (size_t)(bm +      r) * 1024 + (kt) * 32 + cb,                  \
              ASP(bf) + w * 512);                                                  \
    gld_lds16(X  + (size_t)(bm + 64 + r) * 1024 + (kt) * 32 + cb,                  \
              ASP(bf) + 2048 + w * 512);                                           \
    gld_lds16(WT + (size_t)(bn +      r) * 1024 + (kt) * 32 + cb,                  \
              BSP(bf) + w * 512);                                                  \
    gld_lds16(WT + (size_t)(bn + 64 + r) * 1024 + (kt) * 32 + cb,                  \
              BSP(bf) + 2048 + w * 512);                                           \
  } while (0)

  GSTAGE(0, 0);
  GSTAGE(1, 1);
  asm volatile("s_waitcnt vmcnt(4)" ::: "memory");
  __builtin_amdgcn_s_barrier();

  for (int kt = 0; kt < 32; ++kt){
    const int cur = kt % 3;
    if (kt + 2 < 32) GSTAGE(kt + 2, (kt + 2) % 3);
    short8 aA[4], bB[4];
#pragma unroll
    for (int i = 0; i < 4; ++i)
      aA[i] = *(const short8*)(ASP(cur) + (wm * 64 + i * 16 + lr) * 32 + lg * 8);
#pragma unroll
    for (int i = 0; i < 4; ++i)
      bB[i] = *(const short8*)(BSP(cur) + (wn * 64 + i * 16 + lr) * 32 + lg * 8);
    __builtin_amdgcn_s_setprio(1);
#pragma unroll
    for (int mi = 0; mi < 4; ++mi)
#pragma unroll
      for (int ni = 0; ni < 4; ++ni)
        acc[mi][ni] = mfma16(aA[mi], bB[ni], acc[mi][ni]);
    __builtin_amdgcn_s_setprio(0);
    if (kt + 1 < 32){
      asm volatile("s_waitcnt lgkmcnt(0)" ::: "memory");
      if (kt + 2 < 32) asm volatile("s_waitcnt vmcnt(4)" ::: "memory");
      else             asm volatile("s_waitcnt vmcnt(0)" ::: "memory");
      __builtin_amdgcn_s_barrier();
    }
  }
#undef GSTAGE

  // epilogue: frag -> LDS (bf16 + bias) -> coalesced 16B stores
  asm volatile("s_waitcnt lgkmcnt(0)" ::: "memory");
  __builtin_amdgcn_s_barrier();
#pragma unroll
  for (int ni = 0; ni < 4; ++ni){
    int col = wn * 64 + ni * 16 + lr;
    float bv = bias[bn + col];
#pragma unroll
    for (int mi = 0; mi < 4; ++mi){
      int row0 = wm * 64 + mi * 16 + lg * 4;
#pragma unroll
      for (int j = 0; j < 4; ++j)
        LDSB[(row0 + j) * 128 + col] = f2bf(acc[mi][ni][j] + bv);
    }
  }
  asm volatile("s_waitcnt lgkmcnt(0)" ::: "memory");
  __builtin_amdgcn_s_barrier();
#pragma unroll
  for (int i = 0; i < 8; ++i){
    int idx = t + i * 256;
    int row = idx >> 4;
    int c8  = idx & 15;
    short8 v = *(const short8*)&LDSB[row * 128 + c8 * 8];
    *(short8*)(out + (size_t)(bm + row) * 1024 + bn + c8 * 8) = v;
  }
#undef ASP
#undef BSP
}

// ---------------- h = leaky(LN(g1)); 2 rows/block, 16B loads ----------------
__global__ __launch_bounds__(256) void ln_leaky(const unsigned short* __restrict__ in,
                                                const float* __restrict__ g,
                                                const float* __restrict__ bt,
                                                unsigned short* __restrict__ out){
  int rg = threadIdx.x >> 7, tt = threadIdx.x & 127;
  int row = blockIdx.x * 2 + rg;
  short8 iv = *(const short8*)(in + (size_t)row * DD + tt * 8);
  float x[8]; float s = 0.f, ssq = 0.f;
#pragma unroll
  for (int i = 0; i < 8; ++i){
    x[i] = bf2f((unsigned short)iv[i]);
    s += x[i]; ssq += x[i] * x[i];
  }
  float2 r = br2(s, ssq);
  float m = r.x * (1.0f / DD);
  float rs = rsqrtf(r.y * (1.0f / DD) - m * m + 1e-5f);
  float4 g0 = *(const float4*)(g + tt * 8), g1 = *(const float4*)(g + tt * 8 + 4);
  float4 b0 = *(const float4*)(bt + tt * 8), b1 = *(const float4*)(bt + tt * 8 + 4);
  float gg[8] = {g0.x,g0.y,g0.z,g0.w,g1.x,g1.y,g1.z,g1.w};
  float bb[8] = {b0.x,b0.y,b0.z,b0.w,b1.x,b1.y,b1.z,b1.w};
  short8 ov;
#pragma unroll
  for (int i = 0; i < 8; ++i){
    float v = (x[i]-m)*rs*gg[i] + bb[i];
    v = v >= 0.f ? v : 0.01f * v;
    ov[i] = (short)f2bf(v);
  }
  *(short8*)(out + (size_t)row * DD + tt * 8) = ov;
}

// ---------------- final: y=leaky(LN(g2)); y2=LN(y1+y); out=LN(y1+y2); 2 rows/block ----------------
__global__ __launch_bounds__(256) void final_kern(const unsigned short* __restrict__ g2,
                                                  const unsigned short* __restrict__ y1,
                                                  const float* __restrict__ ln2g, const float* __restrict__ ln2b,
                                                  const float* __restrict__ anfg, const float* __restrict__ anfb,
                                                  const float* __restrict__ an2g, const float* __restrict__ an2b,
                                                  float* __restrict__ out){
  int rg = threadIdx.x >> 7, tt = threadIdx.x & 127;
  int row = blockIdx.x * 2 + rg;
  short8 iv = *(const short8*)(g2 + (size_t)row * DD + tt * 8);
  short8 yv = *(const short8*)(y1 + (size_t)row * DD + tt * 8);
  float x[8], yy1[8]; float s = 0.f, ssq = 0.f;
#pragma unroll
  for (int i = 0; i < 8; ++i){
    x[i] = bf2f((unsigned short)iv[i]);
    yy1[i] = bf2f((unsigned short)yv[i]);
    s += x[i]; ssq += x[i] * x[i];
  }
  float2 r = br2(s, ssq);
  float m = r.x * (1.0f / DD);
  float rs = rsqrtf(r.y * (1.0f / DD) - m * m + 1e-5f);
  float4 p0, p1;
  p0 = *(const float4*)(ln2g + tt * 8); p1 = *(const float4*)(ln2g + tt * 8 + 4);
  float gg[8] = {p0.x,p0.y,p0.z,p0.w,p1.x,p1.y,p1.z,p1.w};
  p0 = *(const float4*)(ln2b + tt * 8); p1 = *(const float4*)(ln2b + tt * 8 + 4);
  float bb[8] = {p0.x,p0.y,p0.z,p0.w,p1.x,p1.y,p1.z,p1.w};
  float y[8];
#pragma unroll
  for (int i = 0; i < 8; ++i){
    float v = (x[i]-m)*rs*gg[i] + bb[i];
    y[i] = v >= 0.f ? v : 0.01f * v;
  }

  float tv[8]; s = 0.f; ssq = 0.f;
#pragma unroll
  for (int i = 0; i < 8; ++i){ tv[i] = yy1[i] + y[i]; s += tv[i]; ssq += tv[i]*tv[i]; }
  r = br2(s, ssq);
  m = r.x * (1.0f / DD);
  rs = rsqrtf(r.y * (1.0f / DD) - m*m + 1e-5f);
  p0 = *(const float4*)(anfg + tt * 8); p1 = *(const float4*)(anfg + tt * 8 + 4);
  float gg2[8] = {p0.x,p0.y,p0.z,p0.w,p1.x,p1.y,p1.z,p1.w};
  p0 = *(const float4*)(anfb + tt * 8); p1 = *(const float4*)(anfb + tt * 8 + 4);
  float bb2[8] = {p0.x,p0.y,p0.z,p0.w,p1.x,p1.y,p1.z,p1.w};
  float y2[8];
#pragma unroll
  for (int i = 0; i < 8; ++i) y2[i] = (tv[i]-m)*rs*gg2[i] + bb2[i];

  float u[8]; s = 0.f; ssq = 0.f;
#pragma unroll
  for (int i = 0; i < 8; ++i){ u[i] = yy1[i] + y2[i]; s += u[i]; ssq += u[i]*u[i]; }
  r = br2(s, ssq);
  m = r.x * (1.0f / DD);
  rs = rsqrtf(r.y * (1.0f / DD) - m*m + 1e-5f);
  p0 = *(const float4*)(an2g + tt * 8); p1 = *(const float4*)(an2g + tt * 8 + 4);
  float gg3[8] = {p0.x,p0.y,p0.z,p0.w,p1.x,p1.y,p1.z,p1.w};
  p0 = *(const float4*)(an2b + tt * 8); p1 = *(const float4*)(an2b + tt * 8 + 4);
  float bb3[8] = {p0.x,p0.y,p0.z,p0.w,p1.x,p1.y,p1.z,p1.w};
  float4 o0 = { (u[0]-m)*rs*gg3[0] + bb3[0], (u[1]-m)*rs*gg3[1] + bb3[1],
                (u[2]-m)*rs*gg3[2] + bb3[2], (u[3]-m)*rs*gg3[3] + bb3[3] };
  float4 o1 = { (u[4]-m)*rs*gg3[4] + bb3[4], (u[5]-m)*rs*gg3[5] + bb3[5],
                (u[6]-m)*rs*gg3[6] + bb3[6], (u[7]-m)*rs*gg3[7] + bb3[7] };
  *(float4*)(out + (size_t)row * DD + tt * 8) = o0;
  *(float4*)(out + (size_t)row * DD + tt * 8 + 4) = o1;
}

extern "C" void kernel_launch(void* const* d_in, const int* in_sizes, int n_in,
                              void* d_out, int out_size, void* d_ws, size_t ws_size,
                              hipStream_t stream){
  const float* q    = (const float*)d_in[0];
  const int* masks  = (const int*)d_in[1];
  const float* w1   = (const float*)d_in[2];
  const float* b1   = (const float*)d_in[3];
  const float* ln1g = (const float*)d_in[4];
  const float* ln1b = (const float*)d_in[5];
  const float* w2   = (const float*)d_in[6];
  const float* b2   = (const float*)d_in[7];
  const float* ln2g = (const float*)d_in[8];
  const float* ln2b = (const float*)d_in[9];
  const float* anfg = (const float*)d_in[10];
  const float* anfb = (const float*)d_in[11];
  const float* an1g = (const float*)d_in[12];
  const float* an1b = (const float*)d_in[13];
  const float* an2g = (const float*)d_in[14];
  const float* an2b = (const float*)d_in[15];

  char* ws = (char*)d_ws;
  unsigned short* w1T  = (unsigned short*)(ws + 0);          //  2 MB
  unsigned short* w2T  = (unsigned short*)(ws + 2097152);    //  2 MB
  unsigned short* kf   = (unsigned short*)(ws + 4194304);    // 16 MB  (reused: g1)
  unsigned short* vf   = (unsigned short*)(ws + 20971520);   // 16 MB  (reused: h)
  unsigned short* attn = (unsigned short*)(ws + 37748736);   // 16 MB  (reused: g2)
  unsigned short* y1b  = (unsigned short*)(ws + 54525952);   // 16 MB
  unsigned short* qb   = (unsigned short*)(ws + 71303168);   // 16 MB  -> total 88 MB
  unsigned short* g1   = kf;
  unsigned short* hbuf = vf;
  unsigned short* g2   = attn;
  float* outp = (float*)d_out;

  prep_w<<<dim3(16, 16, 2), 256, 0, stream>>>(w1, w2, w1T, w2T);
  prep_q<<<dim3(2048), 256, 0, stream>>>(q, kf, vf, qb);
  attn_kern<<<dim3(128, 4), 256, 0, stream>>>(kf, vf, masks, attn);
  addnorm1<<<dim3(4096), 256, 0, stream>>>(qb, attn, an1g, an1b, y1b);
  gemm_bias<<<dim3(64, 8), 256, 0, stream>>>(y1b, w1T, b1, g1);
  ln_leaky<<<dim3(4096), 256, 0, stream>>>(g1, ln1g, ln1b, hbuf);
  gemm_bias<<<dim3(64, 8), 256, 0, stream>>>(hbuf, w2T, b2, g2);
  final_kern<<<dim3(4096), 256, 0, stream>>>(g2, y1b, ln2g, ln2b, anfg, anfb, an2g, an2b, outp);
}